// Round 1
// baseline (4033.814 us; speedup 1.0000x reference)
//
#include <hip/hip_runtime.h>
#include <math.h>

#define NN 20000
#define NE 320000
#define NL 3
#define EPSV 1e-5f

// stats layout (floats, relative to f_stats)
#define S_ESUM 0      // edge BN sums [128] + sumsq [128]
#define S_ESC  256    // edge BN scale [128]
#define S_ESH  384    // edge BN shift [128]
#define S_NSUM 512    // node BN sums [128] + sumsq [128]
#define S_NSC  768
#define S_NSH  896
#define S_HSUM 1024   // column sums of final h [128]
#define S_TOTAL 1152

__device__ __forceinline__ float sigf(float x) { return 1.0f / (1.0f + expf(-x)); }

// ---- shared GEMM tile body: acc[8][4] += A[base+64rows, 128] @ W[128,128] tile ----
__device__ __forceinline__ void gemm_tile(
    const float* __restrict__ A, const float* __restrict__ W, int M, long base,
    int tid, int tx, int ty, float acc[8][4], float (*As)[36], float (*Ws)[132])
{
  for (int k0 = 0; k0 < 128; k0 += 32) {
    {
      int r = tid >> 3, cv = tid & 7;
      #pragma unroll
      for (int rr = 0; rr < 2; ++rr) {
        int row = r + rr * 32;
        long grow = base + row;
        float4 v = make_float4(0.f, 0.f, 0.f, 0.f);
        if (grow < M) v = *(const float4*)(A + grow * 128 + k0 + cv * 4);
        *(float4*)&As[row][cv * 4] = v;
      }
      #pragma unroll
      for (int i = 0; i < 4; ++i) {
        int idx = tid + i * 256;
        int wr = idx >> 5, wc = idx & 31;
        *(float4*)&Ws[wr][wc * 4] = *(const float4*)(W + (long)(k0 + wr) * 128 + wc * 4);
      }
    }
    __syncthreads();
    #pragma unroll
    for (int kk = 0; kk < 32; kk += 4) {
      float4 w0 = *(const float4*)&Ws[kk + 0][tx * 4];
      float4 w1 = *(const float4*)&Ws[kk + 1][tx * 4];
      float4 w2 = *(const float4*)&Ws[kk + 2][tx * 4];
      float4 w3 = *(const float4*)&Ws[kk + 3][tx * 4];
      #pragma unroll
      for (int r2 = 0; r2 < 8; ++r2) {
        float4 av = *(const float4*)&As[ty * 8 + r2][kk];
        acc[r2][0] = fmaf(av.w, w3.x, fmaf(av.z, w2.x, fmaf(av.y, w1.x, fmaf(av.x, w0.x, acc[r2][0]))));
        acc[r2][1] = fmaf(av.w, w3.y, fmaf(av.z, w2.y, fmaf(av.y, w1.y, fmaf(av.x, w0.y, acc[r2][1]))));
        acc[r2][2] = fmaf(av.w, w3.z, fmaf(av.z, w2.z, fmaf(av.y, w1.z, fmaf(av.x, w0.z, acc[r2][2]))));
        acc[r2][3] = fmaf(av.w, w3.w, fmaf(av.z, w2.w, fmaf(av.y, w1.w, fmaf(av.x, w0.w, acc[r2][3]))));
      }
    }
    __syncthreads();
  }
}

// ---- C[M,128] = A[M,128] @ W[128,128] + b ----
__global__ __launch_bounds__(256) void gemm128(
    const float* __restrict__ A, const float* __restrict__ W,
    const float* __restrict__ bias, float* __restrict__ C, int M)
{
  __shared__ float As[64][36];
  __shared__ float Ws[32][132];
  int tid = threadIdx.x, tx = tid & 31, ty = tid >> 5;
  long base = (long)blockIdx.x * 64;
  float acc[8][4];
  #pragma unroll
  for (int r = 0; r < 8; ++r) { acc[r][0] = 0.f; acc[r][1] = 0.f; acc[r][2] = 0.f; acc[r][3] = 0.f; }
  gemm_tile(A, W, M, base, tid, tx, ty, acc, As, Ws);
  float4 b4 = *(const float4*)(bias + tx * 4);
  #pragma unroll
  for (int r = 0; r < 8; ++r) {
    long grow = base + ty * 8 + r;
    if (grow < M)
      *(float4*)(C + grow * 128 + tx * 4) =
          make_float4(acc[r][0] + b4.x, acc[r][1] + b4.y, acc[r][2] + b4.z, acc[r][3] + b4.w);
  }
}

// ---- 4 node GEMMs (A,B,D,E linears) in one launch: blockIdx.y selects matrix ----
__global__ __launch_bounds__(256) void gemm128_x4(
    const float* __restrict__ A, const float* __restrict__ Wl, const float* __restrict__ bl,
    float* __restrict__ o0, float* __restrict__ o1, float* __restrict__ o2, float* __restrict__ o3, int M)
{
  __shared__ float As[64][36];
  __shared__ float Ws[32][132];
  int y = blockIdx.y;
  int widx = (y < 2) ? y : y + 1;  // {0,1,3,4}
  const float* W = Wl + (long)widx * 128 * 128;
  const float* bias = bl + (long)widx * 128;
  float* C = (y == 0) ? o0 : (y == 1) ? o1 : (y == 2) ? o2 : o3;
  int tid = threadIdx.x, tx = tid & 31, ty = tid >> 5;
  long base = (long)blockIdx.x * 64;
  float acc[8][4];
  #pragma unroll
  for (int r = 0; r < 8; ++r) { acc[r][0] = 0.f; acc[r][1] = 0.f; acc[r][2] = 0.f; acc[r][3] = 0.f; }
  gemm_tile(A, W, M, base, tid, tx, ty, acc, As, Ws);
  float4 b4 = *(const float4*)(bias + tx * 4);
  #pragma unroll
  for (int r = 0; r < 8; ++r) {
    long grow = base + ty * 8 + r;
    if (grow < M)
      *(float4*)(C + grow * 128 + tx * 4) =
          make_float4(acc[r][0] + b4.x, acc[r][1] + b4.y, acc[r][2] + b4.z, acc[r][3] + b4.w);
  }
}

// ---- fused edge kernel: Ce GEMM + e_hat + sigmoid + scatter-add + BN stats ----
__global__ __launch_bounds__(256) void edge_fused(
    const float* __restrict__ e, const float* __restrict__ W, const float* __restrict__ bias,
    const int* __restrict__ src, const int* __restrict__ dst,
    const float* __restrict__ Bh, const float* __restrict__ Dh, const float* __restrict__ Eh,
    float* __restrict__ ehat, float* __restrict__ agg, float* __restrict__ stats, int save_ehat)
{
  __shared__ float As[64][36];
  __shared__ float Ws[32][132];
  __shared__ float red[8][32][8];
  int tid = threadIdx.x, tx = tid & 31, ty = tid >> 5;
  long base = (long)blockIdx.x * 64;
  float acc[8][4];
  #pragma unroll
  for (int r = 0; r < 8; ++r) { acc[r][0] = 0.f; acc[r][1] = 0.f; acc[r][2] = 0.f; acc[r][3] = 0.f; }
  gemm_tile(e, W, NE, base, tid, tx, ty, acc, As, Ws);

  float4 b4 = *(const float4*)(bias + tx * 4);
  float s0 = 0, s1 = 0, s2 = 0, s3 = 0, q0 = 0, q1 = 0, q2 = 0, q3 = 0;
  #pragma unroll
  for (int r = 0; r < 8; ++r) {
    long erow = base + ty * 8 + r;  // NE is exact multiple of 64 -> no bounds check
    int si = src[erow], di = dst[erow];
    float4 dh = *(const float4*)(Dh + (long)di * 128 + tx * 4);
    float4 eh = *(const float4*)(Eh + (long)si * 128 + tx * 4);
    float4 bh = *(const float4*)(Bh + (long)si * 128 + tx * 4);
    float x0 = acc[r][0] + b4.x + dh.x + eh.x;
    float x1 = acc[r][1] + b4.y + dh.y + eh.y;
    float x2 = acc[r][2] + b4.z + dh.z + eh.z;
    float x3 = acc[r][3] + b4.w + dh.w + eh.w;
    if (save_ehat)
      *(float4*)(ehat + erow * 128 + tx * 4) = make_float4(x0, x1, x2, x3);
    s0 += x0; s1 += x1; s2 += x2; s3 += x3;
    q0 += x0 * x0; q1 += x1 * x1; q2 += x2 * x2; q3 += x3 * x3;
    float* ap = agg + (long)di * 128 + tx * 4;
    atomicAdd(ap + 0, sigf(x0) * bh.x);
    atomicAdd(ap + 1, sigf(x1) * bh.y);
    atomicAdd(ap + 2, sigf(x2) * bh.z);
    atomicAdd(ap + 3, sigf(x3) * bh.w);
  }
  if (save_ehat) {  // block-uniform: edge BN stats only needed when e-update will happen
    red[ty][tx][0] = s0; red[ty][tx][1] = s1; red[ty][tx][2] = s2; red[ty][tx][3] = s3;
    red[ty][tx][4] = q0; red[ty][tx][5] = q1; red[ty][tx][6] = q2; red[ty][tx][7] = q3;
    __syncthreads();
    if (ty == 0) {
      float a0 = 0, a1 = 0, a2 = 0, a3 = 0, c0 = 0, c1 = 0, c2 = 0, c3 = 0;
      #pragma unroll
      for (int t = 0; t < 8; ++t) {
        a0 += red[t][tx][0]; a1 += red[t][tx][1]; a2 += red[t][tx][2]; a3 += red[t][tx][3];
        c0 += red[t][tx][4]; c1 += red[t][tx][5]; c2 += red[t][tx][6]; c3 += red[t][tx][7];
      }
      atomicAdd(stats + tx * 4 + 0, a0); atomicAdd(stats + tx * 4 + 1, a1);
      atomicAdd(stats + tx * 4 + 2, a2); atomicAdd(stats + tx * 4 + 3, a3);
      atomicAdd(stats + 128 + tx * 4 + 0, c0); atomicAdd(stats + 128 + tx * 4 + 1, c1);
      atomicAdd(stats + 128 + tx * 4 + 2, c2); atomicAdd(stats + 128 + tx * 4 + 3, c3);
    }
  }
}

// ---- node pass 1: x = Ah + agg (in-place over Ah) + node BN stats ----
__global__ __launch_bounds__(256) void node_pass1(
    float* __restrict__ x, const float* __restrict__ agg, float* __restrict__ sums)
{
  __shared__ float red[8][32][8];
  int tid = threadIdx.x, tx = tid & 31, ty = tid >> 5;
  long row = (long)blockIdx.x * 8 + ty;  // grid 2500 * 8 = 20000 exact
  float4 a = *(const float4*)(x + row * 128 + tx * 4);
  float4 g = *(const float4*)(agg + row * 128 + tx * 4);
  float x0 = a.x + g.x, x1 = a.y + g.y, x2 = a.z + g.z, x3 = a.w + g.w;
  *(float4*)(x + row * 128 + tx * 4) = make_float4(x0, x1, x2, x3);
  red[ty][tx][0] = x0; red[ty][tx][1] = x1; red[ty][tx][2] = x2; red[ty][tx][3] = x3;
  red[ty][tx][4] = x0 * x0; red[ty][tx][5] = x1 * x1; red[ty][tx][6] = x2 * x2; red[ty][tx][7] = x3 * x3;
  __syncthreads();
  if (ty == 0) {
    float a0 = 0, a1 = 0, a2 = 0, a3 = 0, c0 = 0, c1 = 0, c2 = 0, c3 = 0;
    #pragma unroll
    for (int t = 0; t < 8; ++t) {
      a0 += red[t][tx][0]; a1 += red[t][tx][1]; a2 += red[t][tx][2]; a3 += red[t][tx][3];
      c0 += red[t][tx][4]; c1 += red[t][tx][5]; c2 += red[t][tx][6]; c3 += red[t][tx][7];
    }
    atomicAdd(sums + tx * 4 + 0, a0); atomicAdd(sums + tx * 4 + 1, a1);
    atomicAdd(sums + tx * 4 + 2, a2); atomicAdd(sums + tx * 4 + 3, a3);
    atomicAdd(sums + 128 + tx * 4 + 0, c0); atomicAdd(sums + 128 + tx * 4 + 1, c1);
    atomicAdd(sums + 128 + tx * 4 + 2, c2); atomicAdd(sums + 128 + tx * 4 + 3, c3);
  }
}

// ---- finalize BN: scale = g*rsqrt(var+eps), shift = b - scale*mu ----
__global__ void finalize_bn(const float* __restrict__ sums, float invn,
                            const float* __restrict__ gamma, const float* __restrict__ beta,
                            float* __restrict__ scale, float* __restrict__ shift)
{
  int c = threadIdx.x;  // 128
  float mu = sums[c] * invn;
  float var = sums[128 + c] * invn - mu * mu;
  float sc = gamma[c] * rsqrtf(var + EPSV);
  scale[c] = sc;
  shift[c] = beta[c] - sc * mu;
}

// ---- pass 2 (residual + relu(bn(x))): dsta += max(0, scale*x + shift) ----
__global__ __launch_bounds__(256) void pass2(
    float* __restrict__ dsta, const float* __restrict__ xv,
    const float* __restrict__ scale, const float* __restrict__ shift, long n4)
{
  long i = (long)blockIdx.x * 256 + threadIdx.x;
  if (i >= n4) return;
  int c = (int)(i & 31) * 4;
  float4 x = ((const float4*)xv)[i];
  float4 sc = *(const float4*)(scale + c);
  float4 sh = *(const float4*)(shift + c);
  float4 d = ((const float4*)dsta)[i];
  d.x += fmaxf(fmaf(sc.x, x.x, sh.x), 0.f);
  d.y += fmaxf(fmaf(sc.y, x.y, sh.y), 0.f);
  d.z += fmaxf(fmaf(sc.z, x.z, sh.z), 0.f);
  d.w += fmaxf(fmaf(sc.w, x.w, sh.w), 0.f);
  ((float4*)dsta)[i] = d;
}

// ---- column sums of h (for final mean) ----
__global__ __launch_bounds__(256) void colsum(const float* __restrict__ h, float* __restrict__ out)
{
  __shared__ float red[8][32][4];
  int tid = threadIdx.x, tx = tid & 31, ty = tid >> 5;
  long row = (long)blockIdx.x * 8 + ty;
  float4 v = *(const float4*)(h + row * 128 + tx * 4);
  red[ty][tx][0] = v.x; red[ty][tx][1] = v.y; red[ty][tx][2] = v.z; red[ty][tx][3] = v.w;
  __syncthreads();
  if (ty == 0) {
    float a0 = 0, a1 = 0, a2 = 0, a3 = 0;
    #pragma unroll
    for (int t = 0; t < 8; ++t) { a0 += red[t][tx][0]; a1 += red[t][tx][1]; a2 += red[t][tx][2]; a3 += red[t][tx][3]; }
    atomicAdd(out + tx * 4 + 0, a0); atomicAdd(out + tx * 4 + 1, a1);
    atomicAdd(out + tx * 4 + 2, a2); atomicAdd(out + tx * 4 + 3, a3);
  }
}

// ---- classifier head: out = relu(mean_h @ W1 + b1) @ W2 + b2 ----
__global__ void cls_head(const float* __restrict__ hsum,
                         const float* __restrict__ W1, const float* __restrict__ b1,
                         const float* __restrict__ W2, const float* __restrict__ b2,
                         float* __restrict__ out)
{
  __shared__ float hm[128];
  __shared__ float r1[128];
  int t = threadIdx.x;  // 128 threads
  hm[t] = hsum[t] * (1.0f / NN);
  __syncthreads();
  float v = b1[t];
  for (int k = 0; k < 128; ++k) v = fmaf(hm[k], W1[k * 128 + t], v);
  r1[t] = fmaxf(v, 0.f);
  __syncthreads();
  if (t < 64) {
    float o = b2[t];
    for (int k = 0; k < 128; ++k) o = fmaf(r1[k], W2[k * 64 + t], o);
    out[t] = o;
  }
}

extern "C" void kernel_launch(void* const* d_in, const int* in_sizes, int n_in,
                              void* d_out, int out_size, void* d_ws, size_t ws_size,
                              hipStream_t stream)
{
  const float* h_in  = (const float*)d_in[0];
  const int*   ei    = (const int*)d_in[1];
  const float* eattr = (const float*)d_in[2];
  const float* nW    = (const float*)d_in[3];
  const float* nb    = (const float*)d_in[4];
  const float* eW    = (const float*)d_in[5];
  const float* eb    = (const float*)d_in[6];
  const float* LW    = (const float*)d_in[7];
  const float* LB    = (const float*)d_in[8];
  const float* G     = (const float*)d_in[9];
  const float* Bt    = (const float*)d_in[10];
  const float* W1    = (const float*)d_in[11];
  const float* b1    = (const float*)d_in[12];
  const float* W2    = (const float*)d_in[13];
  const float* b2    = (const float*)d_in[14];
  float* out = (float*)d_out;

  float* ws = (float*)d_ws;
  float* f_h    = ws;                       // 2.56M
  float* f_e    = f_h    + (long)NN * 128;  // 40.96M
  float* f_ehat = f_e    + (long)NE * 128;  // 40.96M
  float* f_A    = f_ehat + (long)NE * 128;  // 2.56M
  float* f_B    = f_A    + (long)NN * 128;
  float* f_D    = f_B    + (long)NN * 128;
  float* f_E    = f_D    + (long)NN * 128;
  float* f_agg  = f_E    + (long)NN * 128;  // 2.56M
  float* f_stats= f_agg  + (long)NN * 128;  // 1152 floats
  const int* src = ei;
  const int* dst = ei + NE;

  // embeddings
  gemm128<<<313, 256, 0, stream>>>(h_in, nW, nb, f_h, NN);
  gemm128<<<5000, 256, 0, stream>>>(eattr, eW, eb, f_e, NE);

  for (int l = 0; l < NL; ++l) {
    const float* Wl = LW + (long)l * 5 * 128 * 128;
    const float* bl = LB + (long)l * 5 * 128;
    int last = (l == NL - 1);

    // Ah,Bh,Dh,Eh
    gemm128_x4<<<dim3(313, 4), 256, 0, stream>>>(f_h, Wl, bl, f_A, f_B, f_D, f_E, NN);
    // zero agg + stats
    hipMemsetAsync(f_agg, 0, ((long)NN * 128 + S_TOTAL) * sizeof(float), stream);
    // fused edge: Ce GEMM + e_hat + sigmoid + scatter + edge BN stats
    edge_fused<<<5000, 256, 0, stream>>>(f_e, Wl + 2 * 128 * 128, bl + 2 * 128, src, dst,
                                         f_B, f_D, f_E, f_ehat, f_agg, f_stats, last ? 0 : 1);
    if (!last)
      finalize_bn<<<1, 128, 0, stream>>>(f_stats + S_ESUM, 1.0f / NE,
                                         G + (l * 2 + 1) * 128, Bt + (l * 2 + 1) * 128,
                                         f_stats + S_ESC, f_stats + S_ESH);
    // node: x = Ah + agg, stats, bn, residual
    node_pass1<<<2500, 256, 0, stream>>>(f_A, f_agg, f_stats + S_NSUM);
    finalize_bn<<<1, 128, 0, stream>>>(f_stats + S_NSUM, 1.0f / NN,
                                       G + (l * 2 + 0) * 128, Bt + (l * 2 + 0) * 128,
                                       f_stats + S_NSC, f_stats + S_NSH);
    pass2<<<2500, 256, 0, stream>>>(f_h, f_A, f_stats + S_NSC, f_stats + S_NSH, (long)NN * 32);
    // edge residual (skipped on last layer: e is dead afterwards)
    if (!last)
      pass2<<<40000, 256, 0, stream>>>(f_e, f_ehat, f_stats + S_ESC, f_stats + S_ESH, (long)NE * 32);
  }

  // final: mean over h rows -> classifier
  colsum<<<2500, 256, 0, stream>>>(f_h, f_stats + S_HSUM);
  cls_head<<<1, 128, 0, stream>>>(f_stats + S_HSUM, W1, b1, W2, b2, out);
}

// Round 4
// 2846.569 us; speedup vs baseline: 1.4171x; 1.4171x over previous
//
#include <hip/hip_runtime.h>
#include <math.h>

#define NN 20000
#define NE 320000
#define NL 3
#define EPSV 1e-5f
#define MAXD 128

// stats layout (floats, relative to f_stats)
#define S_ESUM 0      // edge BN sums [128] + sumsq [128]
#define S_ESC  256    // edge BN scale [128]
#define S_ESH  384    // edge BN shift [128]
#define S_NSUM 512    // node BN sums [128] + sumsq [128]
#define S_NSC  768
#define S_NSH  896
#define S_HSUM 1024   // column sums of final h [128]
#define S_TOTAL 1152

__device__ __forceinline__ float sigf(float x) { return 1.0f / (1.0f + expf(-x)); }

// ---- shared GEMM tile body: acc[8][4] += A[base+64rows, 128] @ W[128,128] tile ----
__device__ __forceinline__ void gemm_tile(
    const float* __restrict__ A, const float* __restrict__ W, int M, long base,
    int tid, int tx, int ty, float acc[8][4], float (*As)[36], float (*Ws)[132])
{
  for (int k0 = 0; k0 < 128; k0 += 32) {
    {
      int r = tid >> 3, cv = tid & 7;
      #pragma unroll
      for (int rr = 0; rr < 2; ++rr) {
        int row = r + rr * 32;
        long grow = base + row;
        float4 v = make_float4(0.f, 0.f, 0.f, 0.f);
        if (grow < M) v = *(const float4*)(A + grow * 128 + k0 + cv * 4);
        *(float4*)&As[row][cv * 4] = v;
      }
      #pragma unroll
      for (int i = 0; i < 4; ++i) {
        int idx = tid + i * 256;
        int wr = idx >> 5, wc = idx & 31;
        *(float4*)&Ws[wr][wc * 4] = *(const float4*)(W + (long)(k0 + wr) * 128 + wc * 4);
      }
    }
    __syncthreads();
    #pragma unroll
    for (int kk = 0; kk < 32; kk += 4) {
      float4 w0 = *(const float4*)&Ws[kk + 0][tx * 4];
      float4 w1 = *(const float4*)&Ws[kk + 1][tx * 4];
      float4 w2 = *(const float4*)&Ws[kk + 2][tx * 4];
      float4 w3 = *(const float4*)&Ws[kk + 3][tx * 4];
      #pragma unroll
      for (int r2 = 0; r2 < 8; ++r2) {
        float4 av = *(const float4*)&As[ty * 8 + r2][kk];
        acc[r2][0] = fmaf(av.w, w3.x, fmaf(av.z, w2.x, fmaf(av.y, w1.x, fmaf(av.x, w0.x, acc[r2][0]))));
        acc[r2][1] = fmaf(av.w, w3.y, fmaf(av.z, w2.y, fmaf(av.y, w1.y, fmaf(av.x, w0.y, acc[r2][1]))));
        acc[r2][2] = fmaf(av.w, w3.z, fmaf(av.z, w2.z, fmaf(av.y, w1.z, fmaf(av.x, w0.z, acc[r2][2]))));
        acc[r2][3] = fmaf(av.w, w3.w, fmaf(av.z, w2.w, fmaf(av.y, w1.w, fmaf(av.x, w0.w, acc[r2][3]))));
      }
    }
    __syncthreads();
  }
}

// ---- C[M,128] = A[M,128] @ W[128,128] + b ----
__global__ __launch_bounds__(256) void gemm128(
    const float* __restrict__ A, const float* __restrict__ W,
    const float* __restrict__ bias, float* __restrict__ C, int M)
{
  __shared__ float As[64][36];
  __shared__ float Ws[32][132];
  int tid = threadIdx.x, tx = tid & 31, ty = tid >> 5;
  long base = (long)blockIdx.x * 64;
  float acc[8][4];
  #pragma unroll
  for (int r = 0; r < 8; ++r) { acc[r][0] = 0.f; acc[r][1] = 0.f; acc[r][2] = 0.f; acc[r][3] = 0.f; }
  gemm_tile(A, W, M, base, tid, tx, ty, acc, As, Ws);
  float4 b4 = *(const float4*)(bias + tx * 4);
  #pragma unroll
  for (int r = 0; r < 8; ++r) {
    long grow = base + ty * 8 + r;
    if (grow < M)
      *(float4*)(C + grow * 128 + tx * 4) =
          make_float4(acc[r][0] + b4.x, acc[r][1] + b4.y, acc[r][2] + b4.z, acc[r][3] + b4.w);
  }
}

// ---- 4 node GEMMs (A,B,D,E linears) in one launch: blockIdx.y selects matrix ----
__global__ __launch_bounds__(256) void gemm128_x4(
    const float* __restrict__ A, const float* __restrict__ Wl, const float* __restrict__ bl,
    float* __restrict__ o0, float* __restrict__ o1, float* __restrict__ o2, float* __restrict__ o3, int M)
{
  __shared__ float As[64][36];
  __shared__ float Ws[32][132];
  int y = blockIdx.y;
  int widx = (y < 2) ? y : y + 1;  // {0,1,3,4}
  const float* W = Wl + (long)widx * 128 * 128;
  const float* bias = bl + (long)widx * 128;
  float* C = (y == 0) ? o0 : (y == 1) ? o1 : (y == 2) ? o2 : o3;
  int tid = threadIdx.x, tx = tid & 31, ty = tid >> 5;
  long base = (long)blockIdx.x * 64;
  float acc[8][4];
  #pragma unroll
  for (int r = 0; r < 8; ++r) { acc[r][0] = 0.f; acc[r][1] = 0.f; acc[r][2] = 0.f; acc[r][3] = 0.f; }
  gemm_tile(A, W, M, base, tid, tx, ty, acc, As, Ws);
  float4 b4 = *(const float4*)(bias + tx * 4);
  #pragma unroll
  for (int r = 0; r < 8; ++r) {
    long grow = base + ty * 8 + r;
    if (grow < M)
      *(float4*)(C + grow * 128 + tx * 4) =
          make_float4(acc[r][0] + b4.x, acc[r][1] + b4.y, acc[r][2] + b4.z, acc[r][3] + b4.w);
  }
}

// ---- fused edge kernel: Ce GEMM + e_hat (+ edge BN stats). NO atomics, NO scatter. ----
__global__ __launch_bounds__(256) void edge_fused(
    const float* __restrict__ e, const float* __restrict__ W, const float* __restrict__ bias,
    const int* __restrict__ src, const int* __restrict__ dst,
    const float* __restrict__ Dh, const float* __restrict__ Eh,
    float* __restrict__ ehat, float* __restrict__ stats, int do_stats)
{
  __shared__ float As[64][36];
  __shared__ float Ws[32][132];
  __shared__ float red[8][32][8];
  int tid = threadIdx.x, tx = tid & 31, ty = tid >> 5;
  long base = (long)blockIdx.x * 64;
  float acc[8][4];
  #pragma unroll
  for (int r = 0; r < 8; ++r) { acc[r][0] = 0.f; acc[r][1] = 0.f; acc[r][2] = 0.f; acc[r][3] = 0.f; }
  gemm_tile(e, W, NE, base, tid, tx, ty, acc, As, Ws);

  float4 b4 = *(const float4*)(bias + tx * 4);
  float s0 = 0, s1 = 0, s2 = 0, s3 = 0, q0 = 0, q1 = 0, q2 = 0, q3 = 0;
  #pragma unroll
  for (int r = 0; r < 8; ++r) {
    long erow = base + ty * 8 + r;  // NE multiple of 64 -> no bounds check
    int si = src[erow], di = dst[erow];
    float4 dh = *(const float4*)(Dh + (long)di * 128 + tx * 4);
    float4 eh = *(const float4*)(Eh + (long)si * 128 + tx * 4);
    float x0 = acc[r][0] + b4.x + dh.x + eh.x;
    float x1 = acc[r][1] + b4.y + dh.y + eh.y;
    float x2 = acc[r][2] + b4.z + dh.z + eh.z;
    float x3 = acc[r][3] + b4.w + dh.w + eh.w;
    *(float4*)(ehat + erow * 128 + tx * 4) = make_float4(x0, x1, x2, x3);
    s0 += x0; s1 += x1; s2 += x2; s3 += x3;
    q0 += x0 * x0; q1 += x1 * x1; q2 += x2 * x2; q3 += x3 * x3;
  }
  if (do_stats) {  // block-uniform branch
    red[ty][tx][0] = s0; red[ty][tx][1] = s1; red[ty][tx][2] = s2; red[ty][tx][3] = s3;
    red[ty][tx][4] = q0; red[ty][tx][5] = q1; red[ty][tx][6] = q2; red[ty][tx][7] = q3;
    __syncthreads();
    if (ty == 0) {
      float a0 = 0, a1 = 0, a2 = 0, a3 = 0, c0 = 0, c1 = 0, c2 = 0, c3 = 0;
      #pragma unroll
      for (int t = 0; t < 8; ++t) {
        a0 += red[t][tx][0]; a1 += red[t][tx][1]; a2 += red[t][tx][2]; a3 += red[t][tx][3];
        c0 += red[t][tx][4]; c1 += red[t][tx][5]; c2 += red[t][tx][6]; c3 += red[t][tx][7];
      }
      atomicAdd(stats + tx * 4 + 0, a0); atomicAdd(stats + tx * 4 + 1, a1);
      atomicAdd(stats + tx * 4 + 2, a2); atomicAdd(stats + tx * 4 + 3, a3);
      atomicAdd(stats + 128 + tx * 4 + 0, c0); atomicAdd(stats + 128 + tx * 4 + 1, c1);
      atomicAdd(stats + 128 + tx * 4 + 2, c2); atomicAdd(stats + 128 + tx * 4 + 3, c3);
    }
  }
}

// ==================== CSR build (by dst), once per call ====================
__global__ __launch_bounds__(256) void hist_dst(const int* __restrict__ dst, int* __restrict__ deg)
{
  int e = blockIdx.x * 256 + threadIdx.x;
  if (e < NE) atomicAdd(&deg[dst[e]], 1);
}

__global__ __launch_bounds__(1024) void scan_deg(const int* __restrict__ deg,
                                                 int* __restrict__ rowstart, int* __restrict__ cursor)
{
  __shared__ int wsum[16];
  __shared__ int carry;
  int tid = threadIdx.x, lane = tid & 63, wid = tid >> 6;  // 16 waves
  if (tid == 0) carry = 0;
  __syncthreads();
  for (int base = 0; base < NN; base += 1024) {
    int i = base + tid;
    int v = (i < NN) ? deg[i] : 0;
    int x = v;
    #pragma unroll
    for (int off = 1; off < 64; off <<= 1) {
      int y = __shfl_up(x, off, 64);
      if (lane >= off) x += y;
    }
    if (lane == 63) wsum[wid] = x;
    __syncthreads();
    int wpref = 0;
    for (int j = 0; j < wid; ++j) wpref += wsum[j];
    int excl = carry + wpref + x - v;
    if (i < NN) { rowstart[i] = excl; cursor[i] = excl; }
    __syncthreads();
    if (tid == 1023) carry = excl + v;
    __syncthreads();
  }
  if (tid == 0) rowstart[NN] = NE;
}

__global__ __launch_bounds__(256) void fill_csr(const int* __restrict__ dst,
                                                int* __restrict__ cursor, int* __restrict__ elist)
{
  int e = blockIdx.x * 256 + threadIdx.x;
  if (e < NE) {
    int p = atomicAdd(&cursor[dst[e]], 1);
    elist[p] = e;
  }
}

// ---- per-node gather: x[n] = Ah[n] + sum_{e in dst-CSR[n]} sigmoid(ehat[e]) * Bh[src[e]] ----
__global__ __launch_bounds__(128) void gather_node(
    const float* __restrict__ ehat, const float* __restrict__ Bh, const int* __restrict__ src,
    const int* __restrict__ rowstart, const int* __restrict__ elist,
    float* __restrict__ x)
{
  __shared__ int eid[MAXD];
  __shared__ int sorted[MAXD];
  __shared__ int esrc[MAXD];
  int n = blockIdx.x;
  int s = rowstart[n], t = rowstart[n + 1];
  int deg = t - s;
  int tid = threadIdx.x;
  int nload = deg < MAXD ? deg : MAXD;
  if (tid < nload) eid[tid] = elist[s + tid];
  __syncthreads();
  if (tid < nload) {  // rank sort (edge ids unique -> ranks unique) for deterministic order
    int v = eid[tid], r = 0;
    for (int j = 0; j < nload; ++j) r += (eid[j] < v);
    sorted[r] = v;
  }
  __syncthreads();
  if (tid < nload) esrc[tid] = src[sorted[tid]];
  __syncthreads();
  float acc = 0.f;
  for (int k = 0; k < nload; ++k) {
    int e = sorted[k];
    float eh = ehat[(long)e * 128 + tid];
    float bh = Bh[(long)esrc[k] * 128 + tid];
    acc += sigf(eh) * bh;
  }
  for (int k = MAXD; k < deg; ++k) {  // statistically never taken
    int e = elist[s + k];
    float eh = ehat[(long)e * 128 + tid];
    acc += sigf(eh) * Bh[(long)src[e] * 128 + tid];
  }
  long off = (long)n * 128 + tid;
  x[off] += acc;
}

// ---- BN stats over x[M,128]: sums + sumsq (8 rows / block) ----
__global__ __launch_bounds__(256) void stats128(const float* __restrict__ x, float* __restrict__ sums)
{
  __shared__ float red[8][32][8];
  int tid = threadIdx.x, tx = tid & 31, ty = tid >> 5;
  long row = (long)blockIdx.x * 8 + ty;  // grid 2500 * 8 = 20000 exact
  float4 v = *(const float4*)(x + row * 128 + tx * 4);
  red[ty][tx][0] = v.x; red[ty][tx][1] = v.y; red[ty][tx][2] = v.z; red[ty][tx][3] = v.w;
  red[ty][tx][4] = v.x * v.x; red[ty][tx][5] = v.y * v.y; red[ty][tx][6] = v.z * v.z; red[ty][tx][7] = v.w * v.w;
  __syncthreads();
  if (ty == 0) {
    float a0 = 0, a1 = 0, a2 = 0, a3 = 0, c0 = 0, c1 = 0, c2 = 0, c3 = 0;
    #pragma unroll
    for (int t = 0; t < 8; ++t) {
      a0 += red[t][tx][0]; a1 += red[t][tx][1]; a2 += red[t][tx][2]; a3 += red[t][tx][3];
      c0 += red[t][tx][4]; c1 += red[t][tx][5]; c2 += red[t][tx][6]; c3 += red[t][tx][7];
    }
    atomicAdd(sums + tx * 4 + 0, a0); atomicAdd(sums + tx * 4 + 1, a1);
    atomicAdd(sums + tx * 4 + 2, a2); atomicAdd(sums + tx * 4 + 3, a3);
    atomicAdd(sums + 128 + tx * 4 + 0, c0); atomicAdd(sums + 128 + tx * 4 + 1, c1);
    atomicAdd(sums + 128 + tx * 4 + 2, c2); atomicAdd(sums + 128 + tx * 4 + 3, c3);
  }
}

// ---- finalize BN: scale = g*rsqrt(var+eps), shift = b - scale*mu ----
__global__ void finalize_bn(const float* __restrict__ sums, float invn,
                            const float* __restrict__ gamma, const float* __restrict__ beta,
                            float* __restrict__ scale, float* __restrict__ shift)
{
  int c = threadIdx.x;  // 128
  float mu = sums[c] * invn;
  float var = sums[128 + c] * invn - mu * mu;
  float sc = gamma[c] * rsqrtf(var + EPSV);
  scale[c] = sc;
  shift[c] = beta[c] - sc * mu;
}

// ---- pass 2 (residual + relu(bn(x))): dsta += max(0, scale*x + shift) ----
__global__ __launch_bounds__(256) void pass2(
    float* __restrict__ dsta, const float* __restrict__ xv,
    const float* __restrict__ scale, const float* __restrict__ shift, long n4)
{
  long i = (long)blockIdx.x * 256 + threadIdx.x;
  if (i >= n4) return;
  int c = (int)(i & 31) * 4;
  float4 x = ((const float4*)xv)[i];
  float4 sc = *(const float4*)(scale + c);
  float4 sh = *(const float4*)(shift + c);
  float4 d = ((const float4*)dsta)[i];
  d.x += fmaxf(fmaf(sc.x, x.x, sh.x), 0.f);
  d.y += fmaxf(fmaf(sc.y, x.y, sh.y), 0.f);
  d.z += fmaxf(fmaf(sc.z, x.z, sh.z), 0.f);
  d.w += fmaxf(fmaf(sc.w, x.w, sh.w), 0.f);
  ((float4*)dsta)[i] = d;
}

// ---- column sums of h (for final mean) ----
__global__ __launch_bounds__(256) void colsum(const float* __restrict__ h, float* __restrict__ out)
{
  __shared__ float red[8][32][4];
  int tid = threadIdx.x, tx = tid & 31, ty = tid >> 5;
  long row = (long)blockIdx.x * 8 + ty;
  float4 v = *(const float4*)(h + row * 128 + tx * 4);
  red[ty][tx][0] = v.x; red[ty][tx][1] = v.y; red[ty][tx][2] = v.z; red[ty][tx][3] = v.w;
  __syncthreads();
  if (ty == 0) {
    float a0 = 0, a1 = 0, a2 = 0, a3 = 0;
    #pragma unroll
    for (int t = 0; t < 8; ++t) { a0 += red[t][tx][0]; a1 += red[t][tx][1]; a2 += red[t][tx][2]; a3 += red[t][tx][3]; }
    atomicAdd(out + tx * 4 + 0, a0); atomicAdd(out + tx * 4 + 1, a1);
    atomicAdd(out + tx * 4 + 2, a2); atomicAdd(out + tx * 4 + 3, a3);
  }
}

// ---- classifier head: out = relu(mean_h @ W1 + b1) @ W2 + b2 ----
__global__ void cls_head(const float* __restrict__ hsum,
                         const float* __restrict__ W1, const float* __restrict__ b1,
                         const float* __restrict__ W2, const float* __restrict__ b2,
                         float* __restrict__ out)
{
  __shared__ float hm[128];
  __shared__ float r1[128];
  int t = threadIdx.x;  // 128 threads
  hm[t] = hsum[t] * (1.0f / NN);
  __syncthreads();
  float v = b1[t];
  for (int k = 0; k < 128; ++k) v = fmaf(hm[k], W1[k * 128 + t], v);
  r1[t] = fmaxf(v, 0.f);
  __syncthreads();
  if (t < 64) {
    float o = b2[t];
    for (int k = 0; k < 128; ++k) o = fmaf(r1[k], W2[k * 64 + t], o);
    out[t] = o;
  }
}

extern "C" void kernel_launch(void* const* d_in, const int* in_sizes, int n_in,
                              void* d_out, int out_size, void* d_ws, size_t ws_size,
                              hipStream_t stream)
{
  const float* h_in  = (const float*)d_in[0];
  const int*   ei    = (const int*)d_in[1];
  const float* eattr = (const float*)d_in[2];
  const float* nW    = (const float*)d_in[3];
  const float* nb    = (const float*)d_in[4];
  const float* eW    = (const float*)d_in[5];
  const float* eb    = (const float*)d_in[6];
  const float* LW    = (const float*)d_in[7];
  const float* LB    = (const float*)d_in[8];
  const float* G     = (const float*)d_in[9];
  const float* Bt    = (const float*)d_in[10];
  const float* W1    = (const float*)d_in[11];
  const float* b1    = (const float*)d_in[12];
  const float* W2    = (const float*)d_in[13];
  const float* b2    = (const float*)d_in[14];
  float* out = (float*)d_out;

  float* ws = (float*)d_ws;
  float* f_h    = ws;
  float* f_e    = f_h    + (long)NN * 128;
  float* f_ehat = f_e    + (long)NE * 128;
  float* f_A    = f_ehat + (long)NE * 128;
  float* f_B    = f_A    + (long)NN * 128;
  float* f_D    = f_B    + (long)NN * 128;
  float* f_E    = f_D    + (long)NN * 128;
  float* f_stats= f_E    + (long)NN * 128;
  int* i_deg      = (int*)(f_stats + S_TOTAL);
  int* i_rowstart = i_deg + NN;
  int* i_cursor   = i_rowstart + NN + 1;
  int* i_elist    = i_cursor + NN;
  const int* src = ei;
  const int* dst = ei + NE;

  // ---- CSR build (once; reused by all 3 layers) ----
  hipMemsetAsync(i_deg, 0, NN * sizeof(int), stream);
  hist_dst<<<(NE + 255) / 256, 256, 0, stream>>>(dst, i_deg);
  scan_deg<<<1, 1024, 0, stream>>>(i_deg, i_rowstart, i_cursor);
  fill_csr<<<(NE + 255) / 256, 256, 0, stream>>>(dst, i_cursor, i_elist);

  // ---- embeddings ----
  gemm128<<<313, 256, 0, stream>>>(h_in, nW, nb, f_h, NN);
  gemm128<<<5000, 256, 0, stream>>>(eattr, eW, eb, f_e, NE);

  for (int l = 0; l < NL; ++l) {
    const float* Wl = LW + (long)l * 5 * 128 * 128;
    const float* bl = LB + (long)l * 5 * 128;
    int last = (l == NL - 1);

    hipMemsetAsync(f_stats, 0, S_TOTAL * sizeof(float), stream);
    // Ah,Bh,Dh,Eh
    gemm128_x4<<<dim3(313, 4), 256, 0, stream>>>(f_h, Wl, bl, f_A, f_B, f_D, f_E, NN);
    // fused edge: Ce GEMM + e_hat store (+ edge BN stats); no atomics
    edge_fused<<<5000, 256, 0, stream>>>(f_e, Wl + 2 * 128 * 128, bl + 2 * 128, src, dst,
                                         f_D, f_E, f_ehat, f_stats + S_ESUM, last ? 0 : 1);
    if (!last)
      finalize_bn<<<1, 128, 0, stream>>>(f_stats + S_ESUM, 1.0f / NE,
                                         G + (l * 2 + 1) * 128, Bt + (l * 2 + 1) * 128,
                                         f_stats + S_ESC, f_stats + S_ESH);
    // node aggregation via CSR gather (x = Ah + agg, in-place on f_A)
    gather_node<<<NN, 128, 0, stream>>>(f_ehat, f_B, src, i_rowstart, i_elist, f_A);
    stats128<<<2500, 256, 0, stream>>>(f_A, f_stats + S_NSUM);
    finalize_bn<<<1, 128, 0, stream>>>(f_stats + S_NSUM, 1.0f / NN,
                                       G + (l * 2 + 0) * 128, Bt + (l * 2 + 0) * 128,
                                       f_stats + S_NSC, f_stats + S_NSH);
    pass2<<<2500, 256, 0, stream>>>(f_h, f_A, f_stats + S_NSC, f_stats + S_NSH, (long)NN * 32);
    // edge residual (skipped on last layer: e is dead afterwards)
    if (!last)
      pass2<<<40000, 256, 0, stream>>>(f_e, f_ehat, f_stats + S_ESC, f_stats + S_ESH, (long)NE * 32);
  }

  // final: mean over h rows -> classifier
  colsum<<<2500, 256, 0, stream>>>(f_h, f_stats + S_HSUM);
  cls_head<<<1, 128, 0, stream>>>(f_stats + S_HSUM, W1, b1, W2, b2, out);
}

// Round 5
// 2050.173 us; speedup vs baseline: 1.9675x; 1.3885x over previous
//
#include <hip/hip_runtime.h>
#include <math.h>

#define NN 20000
#define NE 320000
#define NL 3
#define EPSV 1e-5f
#define MAXD 128

// stats layout (floats, relative to f_stats)
#define S_ESUM 0
#define S_ESC  256
#define S_ESH  384
#define S_NSUM 512
#define S_NSC  768
#define S_NSH  896
#define S_HSUM 1024
#define S_TOTAL 1152

typedef __attribute__((ext_vector_type(8))) short bf16x8;
typedef __attribute__((ext_vector_type(4))) float f32x4;

__device__ __forceinline__ float sigf(float x) { return 1.0f / (1.0f + expf(-x)); }

// round-to-nearest-even split: a ~= h + l (both bf16), |a-h-l| <= 2^-18|a|
__device__ __forceinline__ void bsplit(float a, unsigned short& h, unsigned short& l)
{
  unsigned u = __float_as_uint(a);
  unsigned rh = (u + 0x7FFFu + ((u >> 16) & 1u)) >> 16;
  h = (unsigned short)rh;
  float hf = __uint_as_float(rh << 16);
  float d = a - hf;
  unsigned v = __float_as_uint(d);
  l = (unsigned short)((v + 0x7FFFu + ((v >> 16) & 1u)) >> 16);
}

// ---- weight pre-split: src fp32 [nmat][k][c] -> dh/dl bf16 [nmat][c][k] (k-transposed) ----
__global__ __launch_bounds__(256) void prep_w(const float* __restrict__ src,
                                              unsigned short* __restrict__ dh,
                                              unsigned short* __restrict__ dl, int nmat)
{
  int idx = blockIdx.x * 256 + threadIdx.x;
  if (idx >= nmat * 16384) return;
  int m = idx >> 14, r = idx & 16383, k = r >> 7, c = r & 127;
  unsigned short h, l;
  bsplit(src[idx], h, l);
  long o = ((long)m << 14) + c * 128 + k;
  dh[o] = h; dl[o] = l;
}

// ---- split-bf16 MFMA GEMM core ----
// Block: 256 thr (4 waves). Tile: M=64 x N=128, K=128 in 4 steps of 32.
// Wave w owns output cols [32w, 32w+32). acc[rg][cg]: rg=4 row-frags(16), cg=2 col-frags(16).
// LDS: Ah/Al [64][40] bf16, Wh/Wl [128][40] bf16 (c-major, k-minor; pad 40 -> 2-way banks).
__device__ __forceinline__ void mfma_core(
    const float* __restrict__ A, long base, int M,
    const unsigned short* __restrict__ Wh_g, const unsigned short* __restrict__ Wl_g,
    int tid, f32x4 acc[4][2],
    unsigned short* Ah, unsigned short* Al, unsigned short* Wh, unsigned short* Wl)
{
  int lane = tid & 63, w = tid >> 6;
  int r16 = lane & 15, g8 = lane >> 4;
  #pragma unroll
  for (int rg = 0; rg < 4; ++rg)
    #pragma unroll
    for (int cg = 0; cg < 2; ++cg)
      acc[rg][cg] = (f32x4){0.f, 0.f, 0.f, 0.f};

  for (int k0 = 0; k0 < 128; k0 += 32) {
    // stage A tile (64 x 32 fp32 -> hi/lo bf16)
    #pragma unroll
    for (int jj = 0; jj < 2; ++jj) {
      int idx = tid + jj * 256;           // 512 float4
      int row = idx >> 3, c4 = idx & 7;
      long grow = base + row;
      float4 v = make_float4(0.f, 0.f, 0.f, 0.f);
      if (grow < M) v = *(const float4*)(A + grow * 128 + k0 + c4 * 4);
      unsigned short h0, l0, h1, l1, h2, l2, h3, l3;
      bsplit(v.x, h0, l0); bsplit(v.y, h1, l1); bsplit(v.z, h2, l2); bsplit(v.w, h3, l3);
      *(uint2*)(Ah + row * 40 + c4 * 4) =
          make_uint2((unsigned)h0 | ((unsigned)h1 << 16), (unsigned)h2 | ((unsigned)h3 << 16));
      *(uint2*)(Al + row * 40 + c4 * 4) =
          make_uint2((unsigned)l0 | ((unsigned)l1 << 16), (unsigned)l2 | ((unsigned)l3 << 16));
    }
    // stage W tiles (pre-split bf16, [c][k] layout): 128 x 32 each
    #pragma unroll
    for (int jj = 0; jj < 2; ++jj) {
      int idx = tid + jj * 256;           // 512 x 16B per array
      int c = idx >> 2, g = idx & 3;
      *(uint4*)(Wh + c * 40 + g * 8) = *(const uint4*)(Wh_g + ((long)c << 7) + k0 + g * 8);
      *(uint4*)(Wl + c * 40 + g * 8) = *(const uint4*)(Wl_g + ((long)c << 7) + k0 + g * 8);
    }
    __syncthreads();
    bf16x8 ah[4], al[4], wh[2], wl[2];
    #pragma unroll
    for (int rg = 0; rg < 4; ++rg) {
      ah[rg] = *(const bf16x8*)(Ah + (rg * 16 + r16) * 40 + g8 * 8);
      al[rg] = *(const bf16x8*)(Al + (rg * 16 + r16) * 40 + g8 * 8);
    }
    #pragma unroll
    for (int cg = 0; cg < 2; ++cg) {
      int c = w * 32 + cg * 16 + r16;
      wh[cg] = *(const bf16x8*)(Wh + c * 40 + g8 * 8);
      wl[cg] = *(const bf16x8*)(Wl + c * 40 + g8 * 8);
    }
    #pragma unroll
    for (int rg = 0; rg < 4; ++rg)
      #pragma unroll
      for (int cg = 0; cg < 2; ++cg) {
        acc[rg][cg] = __builtin_amdgcn_mfma_f32_16x16x32_bf16(ah[rg], wh[cg], acc[rg][cg], 0, 0, 0);
        acc[rg][cg] = __builtin_amdgcn_mfma_f32_16x16x32_bf16(ah[rg], wl[cg], acc[rg][cg], 0, 0, 0);
        acc[rg][cg] = __builtin_amdgcn_mfma_f32_16x16x32_bf16(al[rg], wh[cg], acc[rg][cg], 0, 0, 0);
      }
    __syncthreads();
  }
}

// ---- C[M,128] = A[M,128] @ W + b ----
__global__ __launch_bounds__(256) void gemm128(
    const float* __restrict__ A, const unsigned short* __restrict__ Wh_g,
    const unsigned short* __restrict__ Wl_g, const float* __restrict__ bias,
    float* __restrict__ C, int M)
{
  __shared__ unsigned short Ah[64 * 40], Al[64 * 40], Wh[128 * 40], Wl[128 * 40];
  int tid = threadIdx.x, lane = tid & 63, w = tid >> 6;
  int r16 = lane & 15, g8 = lane >> 4;
  long base = (long)blockIdx.x * 64;
  f32x4 acc[4][2];
  mfma_core(A, base, M, Wh_g, Wl_g, tid, acc, Ah, Al, Wh, Wl);
  #pragma unroll
  for (int cg = 0; cg < 2; ++cg) {
    int col = w * 32 + cg * 16 + r16;
    float b = bias[col];
    #pragma unroll
    for (int rg = 0; rg < 4; ++rg)
      #pragma unroll
      for (int j = 0; j < 4; ++j) {
        long row = base + rg * 16 + g8 * 4 + j;
        if (row < M) C[row * 128 + col] = acc[rg][cg][j] + b;
      }
  }
}

// ---- 4 node GEMMs (A,B,D,E) in one launch ----
__global__ __launch_bounds__(256) void gemm128_x4(
    const float* __restrict__ A, const unsigned short* __restrict__ Wh_l,
    const unsigned short* __restrict__ Wl_l, const float* __restrict__ bl,
    float* __restrict__ o0, float* __restrict__ o1, float* __restrict__ o2,
    float* __restrict__ o3, int M)
{
  __shared__ unsigned short Ah[64 * 40], Al[64 * 40], Wh[128 * 40], Wl[128 * 40];
  int y = blockIdx.y;
  int widx = (y < 2) ? y : y + 1;  // {0,1,3,4}
  const unsigned short* Wh_g = Wh_l + ((long)widx << 14);
  const unsigned short* Wl_g = Wl_l + ((long)widx << 14);
  const float* bias = bl + (long)widx * 128;
  float* C = (y == 0) ? o0 : (y == 1) ? o1 : (y == 2) ? o2 : o3;
  int tid = threadIdx.x, lane = tid & 63, w = tid >> 6;
  int r16 = lane & 15, g8 = lane >> 4;
  long base = (long)blockIdx.x * 64;
  f32x4 acc[4][2];
  mfma_core(A, base, M, Wh_g, Wl_g, tid, acc, Ah, Al, Wh, Wl);
  #pragma unroll
  for (int cg = 0; cg < 2; ++cg) {
    int col = w * 32 + cg * 16 + r16;
    float b = bias[col];
    #pragma unroll
    for (int rg = 0; rg < 4; ++rg)
      #pragma unroll
      for (int j = 0; j < 4; ++j) {
        long row = base + rg * 16 + g8 * 4 + j;
        if (row < M) C[row * 128 + col] = acc[rg][cg][j] + b;
      }
  }
}

// ---- fused edge: Ce GEMM (MFMA) + e_hat = Ce+b+Dh[dst]+Eh[src] (+ BN stats) ----
__global__ __launch_bounds__(256) void edge_fused(
    const float* __restrict__ e, const unsigned short* __restrict__ Wh_g,
    const unsigned short* __restrict__ Wl_g, const float* __restrict__ bias,
    const int* __restrict__ src, const int* __restrict__ dst,
    const float* __restrict__ Dh, const float* __restrict__ Eh,
    float* __restrict__ ehat, float* __restrict__ stats, int do_stats)
{
  __shared__ unsigned short Ah[64 * 40], Al[64 * 40], Wh[128 * 40], Wl[128 * 40];
  int tid = threadIdx.x, lane = tid & 63, w = tid >> 6;
  int r16 = lane & 15, g8 = lane >> 4;
  long base = (long)blockIdx.x * 64;
  f32x4 acc[4][2];
  mfma_core(e, base, NE, Wh_g, Wl_g, tid, acc, Ah, Al, Wh, Wl);

  int colA = w * 32 + r16, colB = colA + 16;
  float bA = bias[colA], bB = bias[colB];
  float s0 = 0.f, s1 = 0.f, q0 = 0.f, q1 = 0.f;
  #pragma unroll
  for (int rg = 0; rg < 4; ++rg)
    #pragma unroll
    for (int j = 0; j < 4; ++j) {
      long erow = base + rg * 16 + g8 * 4 + j;  // NE multiple of 64
      int si = src[erow], di = dst[erow];
      const float* dhp = Dh + (long)di * 128;
      const float* ehp = Eh + (long)si * 128;
      float xA = acc[rg][0][j] + bA + dhp[colA] + ehp[colA];
      float xB = acc[rg][1][j] + bB + dhp[colB] + ehp[colB];
      ehat[erow * 128 + colA] = xA;
      ehat[erow * 128 + colB] = xB;
      s0 += xA; q0 += xA * xA; s1 += xB; q1 += xB * xB;
    }
  if (do_stats) {  // uniform branch; reduce across the 4 lane-groups sharing a column
    s0 += __shfl_xor(s0, 16); s0 += __shfl_xor(s0, 32);
    q0 += __shfl_xor(q0, 16); q0 += __shfl_xor(q0, 32);
    s1 += __shfl_xor(s1, 16); s1 += __shfl_xor(s1, 32);
    q1 += __shfl_xor(q1, 16); q1 += __shfl_xor(q1, 32);
    if (g8 == 0) {
      atomicAdd(stats + colA, s0);       atomicAdd(stats + 128 + colA, q0);
      atomicAdd(stats + colB, s1);       atomicAdd(stats + 128 + colB, q1);
    }
  }
}

// ==================== CSR build (by dst), once per call ====================
__global__ __launch_bounds__(256) void hist_dst(const int* __restrict__ dst, int* __restrict__ deg)
{
  int e = blockIdx.x * 256 + threadIdx.x;
  if (e < NE) atomicAdd(&deg[dst[e]], 1);
}

__global__ __launch_bounds__(1024) void scan_deg(const int* __restrict__ deg,
                                                 int* __restrict__ rowstart, int* __restrict__ cursor)
{
  __shared__ int wsum[16];
  __shared__ int carry;
  int tid = threadIdx.x, lane = tid & 63, wid = tid >> 6;
  if (tid == 0) carry = 0;
  __syncthreads();
  for (int base = 0; base < NN; base += 1024) {
    int i = base + tid;
    int v = (i < NN) ? deg[i] : 0;
    int x = v;
    #pragma unroll
    for (int off = 1; off < 64; off <<= 1) {
      int y = __shfl_up(x, off, 64);
      if (lane >= off) x += y;
    }
    if (lane == 63) wsum[wid] = x;
    __syncthreads();
    int wpref = 0;
    for (int j = 0; j < wid; ++j) wpref += wsum[j];
    int excl = carry + wpref + x - v;
    if (i < NN) { rowstart[i] = excl; cursor[i] = excl; }
    __syncthreads();
    if (tid == 1023) carry = excl + v;
    __syncthreads();
  }
  if (tid == 0) rowstart[NN] = NE;
}

__global__ __launch_bounds__(256) void fill_csr(const int* __restrict__ dst,
                                                int* __restrict__ cursor, int* __restrict__ elist)
{
  int e = blockIdx.x * 256 + threadIdx.x;
  if (e < NE) {
    int p = atomicAdd(&cursor[dst[e]], 1);
    elist[p] = e;
  }
}

// ---- per-node gather: x[n] += sum_{e in dst-CSR[n]} sigmoid(ehat[e]) * Bh[src[e]] ----
__global__ __launch_bounds__(128) void gather_node(
    const float* __restrict__ ehat, const float* __restrict__ Bh, const int* __restrict__ src,
    const int* __restrict__ rowstart, const int* __restrict__ elist,
    float* __restrict__ x)
{
  __shared__ int eid[MAXD];
  __shared__ int sorted[MAXD];
  __shared__ int esrc[MAXD];
  int n = blockIdx.x;
  int s = rowstart[n], t = rowstart[n + 1];
  int deg = t - s;
  int tid = threadIdx.x;
  int nload = deg < MAXD ? deg : MAXD;
  if (tid < nload) eid[tid] = elist[s + tid];
  __syncthreads();
  if (tid < nload) {
    int v = eid[tid], r = 0;
    for (int j = 0; j < nload; ++j) r += (eid[j] < v);
    sorted[r] = v;
  }
  __syncthreads();
  if (tid < nload) esrc[tid] = src[sorted[tid]];
  __syncthreads();
  float acc = 0.f;
  for (int k = 0; k < nload; ++k) {
    int e = sorted[k];
    acc += sigf(ehat[(long)e * 128 + tid]) * Bh[(long)esrc[k] * 128 + tid];
  }
  for (int k = MAXD; k < deg; ++k) {
    int e = elist[s + k];
    acc += sigf(ehat[(long)e * 128 + tid]) * Bh[(long)src[e] * 128 + tid];
  }
  x[(long)n * 128 + tid] += acc;
}

// ---- BN stats over x[M,128] ----
__global__ __launch_bounds__(256) void stats128(const float* __restrict__ x, float* __restrict__ sums)
{
  __shared__ float red[8][32][8];
  int tid = threadIdx.x, tx = tid & 31, ty = tid >> 5;
  long row = (long)blockIdx.x * 8 + ty;
  float4 v = *(const float4*)(x + row * 128 + tx * 4);
  red[ty][tx][0] = v.x; red[ty][tx][1] = v.y; red[ty][tx][2] = v.z; red[ty][tx][3] = v.w;
  red[ty][tx][4] = v.x * v.x; red[ty][tx][5] = v.y * v.y; red[ty][tx][6] = v.z * v.z; red[ty][tx][7] = v.w * v.w;
  __syncthreads();
  if (ty == 0) {
    float a0 = 0, a1 = 0, a2 = 0, a3 = 0, c0 = 0, c1 = 0, c2 = 0, c3 = 0;
    #pragma unroll
    for (int t = 0; t < 8; ++t) {
      a0 += red[t][tx][0]; a1 += red[t][tx][1]; a2 += red[t][tx][2]; a3 += red[t][tx][3];
      c0 += red[t][tx][4]; c1 += red[t][tx][5]; c2 += red[t][tx][6]; c3 += red[t][tx][7];
    }
    atomicAdd(sums + tx * 4 + 0, a0); atomicAdd(sums + tx * 4 + 1, a1);
    atomicAdd(sums + tx * 4 + 2, a2); atomicAdd(sums + tx * 4 + 3, a3);
    atomicAdd(sums + 128 + tx * 4 + 0, c0); atomicAdd(sums + 128 + tx * 4 + 1, c1);
    atomicAdd(sums + 128 + tx * 4 + 2, c2); atomicAdd(sums + 128 + tx * 4 + 3, c3);
  }
}

__global__ void finalize_bn(const float* __restrict__ sums, float invn,
                            const float* __restrict__ gamma, const float* __restrict__ beta,
                            float* __restrict__ scale, float* __restrict__ shift)
{
  int c = threadIdx.x;
  float mu = sums[c] * invn;
  float var = sums[128 + c] * invn - mu * mu;
  float sc = gamma[c] * rsqrtf(var + EPSV);
  scale[c] = sc;
  shift[c] = beta[c] - sc * mu;
}

__global__ __launch_bounds__(256) void pass2(
    float* __restrict__ dsta, const float* __restrict__ xv,
    const float* __restrict__ scale, const float* __restrict__ shift, long n4)
{
  long i = (long)blockIdx.x * 256 + threadIdx.x;
  if (i >= n4) return;
  int c = (int)(i & 31) * 4;
  float4 x = ((const float4*)xv)[i];
  float4 sc = *(const float4*)(scale + c);
  float4 sh = *(const float4*)(shift + c);
  float4 d = ((const float4*)dsta)[i];
  d.x += fmaxf(fmaf(sc.x, x.x, sh.x), 0.f);
  d.y += fmaxf(fmaf(sc.y, x.y, sh.y), 0.f);
  d.z += fmaxf(fmaf(sc.z, x.z, sh.z), 0.f);
  d.w += fmaxf(fmaf(sc.w, x.w, sh.w), 0.f);
  ((float4*)dsta)[i] = d;
}

__global__ __launch_bounds__(256) void colsum(const float* __restrict__ h, float* __restrict__ out)
{
  __shared__ float red[8][32][4];
  int tid = threadIdx.x, tx = tid & 31, ty = tid >> 5;
  long row = (long)blockIdx.x * 8 + ty;
  float4 v = *(const float4*)(h + row * 128 + tx * 4);
  red[ty][tx][0] = v.x; red[ty][tx][1] = v.y; red[ty][tx][2] = v.z; red[ty][tx][3] = v.w;
  __syncthreads();
  if (ty == 0) {
    float a0 = 0, a1 = 0, a2 = 0, a3 = 0;
    #pragma unroll
    for (int t = 0; t < 8; ++t) { a0 += red[t][tx][0]; a1 += red[t][tx][1]; a2 += red[t][tx][2]; a3 += red[t][tx][3]; }
    atomicAdd(out + tx * 4 + 0, a0); atomicAdd(out + tx * 4 + 1, a1);
    atomicAdd(out + tx * 4 + 2, a2); atomicAdd(out + tx * 4 + 3, a3);
  }
}

__global__ void cls_head(const float* __restrict__ hsum,
                         const float* __restrict__ W1, const float* __restrict__ b1,
                         const float* __restrict__ W2, const float* __restrict__ b2,
                         float* __restrict__ out)
{
  __shared__ float hm[128];
  __shared__ float r1[128];
  int t = threadIdx.x;
  hm[t] = hsum[t] * (1.0f / NN);
  __syncthreads();
  float v = b1[t];
  for (int k = 0; k < 128; ++k) v = fmaf(hm[k], W1[k * 128 + t], v);
  r1[t] = fmaxf(v, 0.f);
  __syncthreads();
  if (t < 64) {
    float o = b2[t];
    for (int k = 0; k < 128; ++k) o = fmaf(r1[k], W2[k * 64 + t], o);
    out[t] = o;
  }
}

extern "C" void kernel_launch(void* const* d_in, const int* in_sizes, int n_in,
                              void* d_out, int out_size, void* d_ws, size_t ws_size,
                              hipStream_t stream)
{
  const float* h_in  = (const float*)d_in[0];
  const int*   ei    = (const int*)d_in[1];
  const float* eattr = (const float*)d_in[2];
  const float* nW    = (const float*)d_in[3];
  const float* nb    = (const float*)d_in[4];
  const float* eW    = (const float*)d_in[5];
  const float* eb    = (const float*)d_in[6];
  const float* LW    = (const float*)d_in[7];
  const float* LB    = (const float*)d_in[8];
  const float* G     = (const float*)d_in[9];
  const float* Bt    = (const float*)d_in[10];
  const float* W1    = (const float*)d_in[11];
  const float* b1    = (const float*)d_in[12];
  const float* W2    = (const float*)d_in[13];
  const float* b2    = (const float*)d_in[14];
  float* out = (float*)d_out;

  float* ws = (float*)d_ws;
  float* f_h    = ws;
  float* f_e    = f_h    + (long)NN * 128;
  float* f_ehat = f_e    + (long)NE * 128;
  float* f_A    = f_ehat + (long)NE * 128;
  float* f_B    = f_A    + (long)NN * 128;
  float* f_D    = f_B    + (long)NN * 128;
  float* f_E    = f_D    + (long)NN * 128;
  float* f_stats= f_E    + (long)NN * 128;
  int* i_deg      = (int*)(f_stats + S_TOTAL);
  int* i_rowstart = i_deg + NN;
  int* i_cursor   = i_rowstart + NN + 1;
  int* i_elist    = i_cursor + NN;
  // pre-split weights: 17 mats (0=node_emb, 1=edge_emb, 2+5l+i=layer l mat i), 16B-aligned
  size_t pw_off = ((((char*)(i_elist + NE)) - (char*)d_ws) + 15) & ~(size_t)15;
  unsigned short* pw_h = (unsigned short*)((char*)d_ws + pw_off);
  unsigned short* pw_l = pw_h + (long)17 * 16384;
  const int* src = ei;
  const int* dst = ei + NE;

  // ---- weight pre-split ----
  prep_w<<<64, 256, 0, stream>>>(nW, pw_h, pw_l, 1);
  prep_w<<<64, 256, 0, stream>>>(eW, pw_h + 16384, pw_l + 16384, 1);
  prep_w<<<960, 256, 0, stream>>>(LW, pw_h + 2 * 16384, pw_l + 2 * 16384, 15);

  // ---- CSR build ----
  hipMemsetAsync(i_deg, 0, NN * sizeof(int), stream);
  hist_dst<<<(NE + 255) / 256, 256, 0, stream>>>(dst, i_deg);
  scan_deg<<<1, 1024, 0, stream>>>(i_deg, i_rowstart, i_cursor);
  fill_csr<<<(NE + 255) / 256, 256, 0, stream>>>(dst, i_cursor, i_elist);

  // ---- embeddings ----
  gemm128<<<313, 256, 0, stream>>>(h_in, pw_h, pw_l, nb, f_h, NN);
  gemm128<<<5000, 256, 0, stream>>>(eattr, pw_h + 16384, pw_l + 16384, eb, f_e, NE);

  for (int l = 0; l < NL; ++l) {
    const unsigned short* lwh = pw_h + (long)(2 + l * 5) * 16384;
    const unsigned short* lwl = pw_l + (long)(2 + l * 5) * 16384;
    const float* bl = LB + (long)l * 5 * 128;
    int last = (l == NL - 1);

    hipMemsetAsync(f_stats, 0, S_TOTAL * sizeof(float), stream);
    gemm128_x4<<<dim3(313, 4), 256, 0, stream>>>(f_h, lwh, lwl, bl, f_A, f_B, f_D, f_E, NN);
    edge_fused<<<5000, 256, 0, stream>>>(f_e, lwh + 2 * 16384, lwl + 2 * 16384, bl + 2 * 128,
                                         src, dst, f_D, f_E, f_ehat, f_stats + S_ESUM, last ? 0 : 1);
    if (!last)
      finalize_bn<<<1, 128, 0, stream>>>(f_stats + S_ESUM, 1.0f / NE,
                                         G + (l * 2 + 1) * 128, Bt + (l * 2 + 1) * 128,
                                         f_stats + S_ESC, f_stats + S_ESH);
    gather_node<<<NN, 128, 0, stream>>>(f_ehat, f_B, src, i_rowstart, i_elist, f_A);
    stats128<<<2500, 256, 0, stream>>>(f_A, f_stats + S_NSUM);
    finalize_bn<<<1, 128, 0, stream>>>(f_stats + S_NSUM, 1.0f / NN,
                                       G + (l * 2 + 0) * 128, Bt + (l * 2 + 0) * 128,
                                       f_stats + S_NSC, f_stats + S_NSH);
    pass2<<<2500, 256, 0, stream>>>(f_h, f_A, f_stats + S_NSC, f_stats + S_NSH, (long)NN * 32);
    if (!last)
      pass2<<<40000, 256, 0, stream>>>(f_e, f_ehat, f_stats + S_ESC, f_stats + S_ESH, (long)NE * 32);
  }

  colsum<<<2500, 256, 0, stream>>>(f_h, f_stats + S_HSUM);
  cls_head<<<1, 128, 0, stream>>>(f_stats + S_HSUM, W1, b1, W2, b2, out);
}

// Round 6
// 1340.193 us; speedup vs baseline: 3.0099x; 1.5298x over previous
//
#include <hip/hip_runtime.h>
#include <math.h>

#define NN 20000
#define NE 320000
#define NL 3
#define EPSV 1e-5f
#define MAXD 128

// f_stats layout (floats): only BN scale/shift now (reductions are atomic-free)
#define S_ESC  0
#define S_ESH  128
#define S_NSC  256
#define S_NSH  384
#define S_TOTAL 512

typedef __attribute__((ext_vector_type(8))) short bf16x8;
typedef __attribute__((ext_vector_type(4))) float f32x4;

__device__ __forceinline__ float sigf(float x) { return 1.0f / (1.0f + expf(-x)); }

// round-to-nearest-even split: a ~= h + l (both bf16)
__device__ __forceinline__ void bsplit(float a, unsigned short& h, unsigned short& l)
{
  unsigned u = __float_as_uint(a);
  unsigned rh = (u + 0x7FFFu + ((u >> 16) & 1u)) >> 16;
  h = (unsigned short)rh;
  float hf = __uint_as_float(rh << 16);
  float d = a - hf;
  unsigned v = __float_as_uint(d);
  l = (unsigned short)((v + 0x7FFFu + ((v >> 16) & 1u)) >> 16);
}

// ---- weight pre-split: src fp32 [nmat][k][c] -> dh/dl bf16 [nmat][c][k] (k-transposed) ----
__global__ __launch_bounds__(256) void prep_w(const float* __restrict__ src,
                                              unsigned short* __restrict__ dh,
                                              unsigned short* __restrict__ dl, int nmat)
{
  int idx = blockIdx.x * 256 + threadIdx.x;
  if (idx >= nmat * 16384) return;
  int m = idx >> 14, r = idx & 16383, k = r >> 7, c = r & 127;
  unsigned short h, l;
  bsplit(src[idx], h, l);
  long o = ((long)m << 14) + c * 128 + k;
  dh[o] = h; dl[o] = l;
}

// ---- split-bf16 MFMA GEMM core (tile M=64 x N=128, K=128; 4 waves) ----
__device__ __forceinline__ void mfma_core(
    const float* __restrict__ A, long base, int M,
    const unsigned short* __restrict__ Wh_g, const unsigned short* __restrict__ Wl_g,
    int tid, f32x4 acc[4][2],
    unsigned short* Ah, unsigned short* Al, unsigned short* Wh, unsigned short* Wl)
{
  int lane = tid & 63, w = tid >> 6;
  int r16 = lane & 15, g8 = lane >> 4;
  #pragma unroll
  for (int rg = 0; rg < 4; ++rg)
    #pragma unroll
    for (int cg = 0; cg < 2; ++cg)
      acc[rg][cg] = (f32x4){0.f, 0.f, 0.f, 0.f};

  for (int k0 = 0; k0 < 128; k0 += 32) {
    #pragma unroll
    for (int jj = 0; jj < 2; ++jj) {
      int idx = tid + jj * 256;
      int row = idx >> 3, c4 = idx & 7;
      long grow = base + row;
      float4 v = make_float4(0.f, 0.f, 0.f, 0.f);
      if (grow < M) v = *(const float4*)(A + grow * 128 + k0 + c4 * 4);
      unsigned short h0, l0, h1, l1, h2, l2, h3, l3;
      bsplit(v.x, h0, l0); bsplit(v.y, h1, l1); bsplit(v.z, h2, l2); bsplit(v.w, h3, l3);
      *(uint2*)(Ah + row * 40 + c4 * 4) =
          make_uint2((unsigned)h0 | ((unsigned)h1 << 16), (unsigned)h2 | ((unsigned)h3 << 16));
      *(uint2*)(Al + row * 40 + c4 * 4) =
          make_uint2((unsigned)l0 | ((unsigned)l1 << 16), (unsigned)l2 | ((unsigned)l3 << 16));
    }
    #pragma unroll
    for (int jj = 0; jj < 2; ++jj) {
      int idx = tid + jj * 256;
      int c = idx >> 2, g = idx & 3;
      *(uint4*)(Wh + c * 40 + g * 8) = *(const uint4*)(Wh_g + ((long)c << 7) + k0 + g * 8);
      *(uint4*)(Wl + c * 40 + g * 8) = *(const uint4*)(Wl_g + ((long)c << 7) + k0 + g * 8);
    }
    __syncthreads();
    bf16x8 ah[4], al[4], wh[2], wl[2];
    #pragma unroll
    for (int rg = 0; rg < 4; ++rg) {
      ah[rg] = *(const bf16x8*)(Ah + (rg * 16 + r16) * 40 + g8 * 8);
      al[rg] = *(const bf16x8*)(Al + (rg * 16 + r16) * 40 + g8 * 8);
    }
    #pragma unroll
    for (int cg = 0; cg < 2; ++cg) {
      int c = w * 32 + cg * 16 + r16;
      wh[cg] = *(const bf16x8*)(Wh + c * 40 + g8 * 8);
      wl[cg] = *(const bf16x8*)(Wl + c * 40 + g8 * 8);
    }
    #pragma unroll
    for (int rg = 0; rg < 4; ++rg)
      #pragma unroll
      for (int cg = 0; cg < 2; ++cg) {
        acc[rg][cg] = __builtin_amdgcn_mfma_f32_16x16x32_bf16(ah[rg], wh[cg], acc[rg][cg], 0, 0, 0);
        acc[rg][cg] = __builtin_amdgcn_mfma_f32_16x16x32_bf16(ah[rg], wl[cg], acc[rg][cg], 0, 0, 0);
        acc[rg][cg] = __builtin_amdgcn_mfma_f32_16x16x32_bf16(al[rg], wh[cg], acc[rg][cg], 0, 0, 0);
      }
    __syncthreads();
  }
}

// ---- C[M,128] = A[M,128] @ W + b ----
__global__ __launch_bounds__(256) void gemm128(
    const float* __restrict__ A, const unsigned short* __restrict__ Wh_g,
    const unsigned short* __restrict__ Wl_g, const float* __restrict__ bias,
    float* __restrict__ C, int M)
{
  __shared__ unsigned short Ah[64 * 40], Al[64 * 40], Wh[128 * 40], Wl[128 * 40];
  int tid = threadIdx.x, lane = tid & 63, w = tid >> 6;
  int r16 = lane & 15, g8 = lane >> 4;
  long base = (long)blockIdx.x * 64;
  f32x4 acc[4][2];
  mfma_core(A, base, M, Wh_g, Wl_g, tid, acc, Ah, Al, Wh, Wl);
  #pragma unroll
  for (int cg = 0; cg < 2; ++cg) {
    int col = w * 32 + cg * 16 + r16;
    float b = bias[col];
    #pragma unroll
    for (int rg = 0; rg < 4; ++rg)
      #pragma unroll
      for (int j = 0; j < 4; ++j) {
        long row = base + rg * 16 + g8 * 4 + j;
        if (row < M) C[row * 128 + col] = acc[rg][cg][j] + b;
      }
  }
}

// ---- 4 node GEMMs (A,B,D,E) in one launch ----
__global__ __launch_bounds__(256) void gemm128_x4(
    const float* __restrict__ A, const unsigned short* __restrict__ Wh_l,
    const unsigned short* __restrict__ Wl_l, const float* __restrict__ bl,
    float* __restrict__ o0, float* __restrict__ o1, float* __restrict__ o2,
    float* __restrict__ o3, int M)
{
  __shared__ unsigned short Ah[64 * 40], Al[64 * 40], Wh[128 * 40], Wl[128 * 40];
  int y = blockIdx.y;
  int widx = (y < 2) ? y : y + 1;  // {0,1,3,4}
  const unsigned short* Wh_g = Wh_l + ((long)widx << 14);
  const unsigned short* Wl_g = Wl_l + ((long)widx << 14);
  const float* bias = bl + (long)widx * 128;
  float* C = (y == 0) ? o0 : (y == 1) ? o1 : (y == 2) ? o2 : o3;
  int tid = threadIdx.x, lane = tid & 63, w = tid >> 6;
  int r16 = lane & 15, g8 = lane >> 4;
  long base = (long)blockIdx.x * 64;
  f32x4 acc[4][2];
  mfma_core(A, base, M, Wh_g, Wl_g, tid, acc, Ah, Al, Wh, Wl);
  #pragma unroll
  for (int cg = 0; cg < 2; ++cg) {
    int col = w * 32 + cg * 16 + r16;
    float b = bias[col];
    #pragma unroll
    for (int rg = 0; rg < 4; ++rg)
      #pragma unroll
      for (int j = 0; j < 4; ++j) {
        long row = base + rg * 16 + g8 * 4 + j;
        if (row < M) C[row * 128 + col] = acc[rg][cg][j] + b;
      }
  }
}

// ---- fused edge: Ce GEMM (MFMA) + e_hat = Ce+b+Dh[dst]+Eh[src] (+ per-block BN partials) ----
__global__ __launch_bounds__(256) void edge_fused(
    const float* __restrict__ e, const unsigned short* __restrict__ Wh_g,
    const unsigned short* __restrict__ Wl_g, const float* __restrict__ bias,
    const int* __restrict__ src, const int* __restrict__ dst,
    const float* __restrict__ Dh, const float* __restrict__ Eh,
    float* __restrict__ ehat, float* __restrict__ epart, int do_stats)
{
  __shared__ unsigned short Ah[64 * 40], Al[64 * 40], Wh[128 * 40], Wl[128 * 40];
  int tid = threadIdx.x, lane = tid & 63, w = tid >> 6;
  int r16 = lane & 15, g8 = lane >> 4;
  long base = (long)blockIdx.x * 64;
  f32x4 acc[4][2];
  mfma_core(e, base, NE, Wh_g, Wl_g, tid, acc, Ah, Al, Wh, Wl);

  int colA = w * 32 + r16, colB = colA + 16;
  float bA = bias[colA], bB = bias[colB];
  float s0 = 0.f, s1 = 0.f, q0 = 0.f, q1 = 0.f;
  #pragma unroll
  for (int rg = 0; rg < 4; ++rg)
    #pragma unroll
    for (int j = 0; j < 4; ++j) {
      long erow = base + rg * 16 + g8 * 4 + j;  // NE multiple of 64
      int si = src[erow], di = dst[erow];
      const float* dhp = Dh + (long)di * 128;
      const float* ehp = Eh + (long)si * 128;
      float xA = acc[rg][0][j] + bA + dhp[colA] + ehp[colA];
      float xB = acc[rg][1][j] + bB + dhp[colB] + ehp[colB];
      ehat[erow * 128 + colA] = xA;
      ehat[erow * 128 + colB] = xB;
      s0 += xA; q0 += xA * xA; s1 += xB; q1 += xB * xB;
    }
  if (do_stats) {  // uniform; reduce the 4 lane-groups sharing a column, write block partial
    s0 += __shfl_xor(s0, 16); s0 += __shfl_xor(s0, 32);
    q0 += __shfl_xor(q0, 16); q0 += __shfl_xor(q0, 32);
    s1 += __shfl_xor(s1, 16); s1 += __shfl_xor(s1, 32);
    q1 += __shfl_xor(q1, 16); q1 += __shfl_xor(q1, 32);
    if (g8 == 0) {
      float* bp = epart + (long)blockIdx.x * 256;
      bp[colA] = s0;       bp[128 + colA] = q0;
      bp[colB] = s1;       bp[128 + colB] = q1;
    }
  }
}

// ---- generic: out[b][256] = sum of `groups` consecutive 256-float rows of in ----
__global__ __launch_bounds__(256) void reduce_part(const float* __restrict__ in,
                                                   float* __restrict__ outp, int groups)
{
  int t = threadIdx.x;
  long base = (long)blockIdx.x * groups * 256;
  float acc = 0.f;
  for (int i = 0; i < groups; ++i) acc += in[base + i * 256 + t];
  outp[(long)blockIdx.x * 256 + t] = acc;
}

// ---- finalize BN from partials: thread c sums part[p][c], part[p][128+c] ----
__global__ void finalize_bn_p(const float* __restrict__ part, int np, float invn,
                              const float* __restrict__ gamma, const float* __restrict__ beta,
                              float* __restrict__ scale, float* __restrict__ shift)
{
  int c = threadIdx.x;  // 128
  float s = 0.f, q = 0.f;
  for (int p = 0; p < np; ++p) {
    s += part[(long)p * 256 + c];
    q += part[(long)p * 256 + 128 + c];
  }
  float mu = s * invn;
  float var = q * invn - mu * mu;
  float sc = gamma[c] * rsqrtf(var + EPSV);
  scale[c] = sc;
  shift[c] = beta[c] - sc * mu;
}

// ==================== CSR build (by dst), once per call ====================
__global__ __launch_bounds__(256) void hist_dst(const int* __restrict__ dst, int* __restrict__ deg)
{
  int e = blockIdx.x * 256 + threadIdx.x;
  if (e < NE) atomicAdd(&deg[dst[e]], 1);
}

__global__ __launch_bounds__(1024) void scan_deg(const int* __restrict__ deg,
                                                 int* __restrict__ rowstart, int* __restrict__ cursor)
{
  __shared__ int wsum[16];
  __shared__ int carry;
  int tid = threadIdx.x, lane = tid & 63, wid = tid >> 6;
  if (tid == 0) carry = 0;
  __syncthreads();
  for (int base = 0; base < NN; base += 1024) {
    int i = base + tid;
    int v = (i < NN) ? deg[i] : 0;
    int x = v;
    #pragma unroll
    for (int off = 1; off < 64; off <<= 1) {
      int y = __shfl_up(x, off, 64);
      if (lane >= off) x += y;
    }
    if (lane == 63) wsum[wid] = x;
    __syncthreads();
    int wpref = 0;
    for (int j = 0; j < wid; ++j) wpref += wsum[j];
    int excl = carry + wpref + x - v;
    if (i < NN) { rowstart[i] = excl; cursor[i] = excl; }
    __syncthreads();
    if (tid == 1023) carry = excl + v;
    __syncthreads();
  }
  if (tid == 0) rowstart[NN] = NE;
}

__global__ __launch_bounds__(256) void fill_csr(const int* __restrict__ dst,
                                                int* __restrict__ cursor, int* __restrict__ elist)
{
  int e = blockIdx.x * 256 + threadIdx.x;
  if (e < NE) {
    int p = atomicAdd(&cursor[dst[e]], 1);
    elist[p] = e;
  }
}

// ---- per-node gather: x[n] += sum_{e in dst-CSR[n]} sigmoid(ehat[e]) * Bh[src[e]] ----
__global__ __launch_bounds__(128) void gather_node(
    const float* __restrict__ ehat, const float* __restrict__ Bh, const int* __restrict__ src,
    const int* __restrict__ rowstart, const int* __restrict__ elist,
    float* __restrict__ x)
{
  __shared__ int eid[MAXD];
  __shared__ int sorted[MAXD];
  __shared__ int esrc[MAXD];
  int n = blockIdx.x;
  int s = rowstart[n], t = rowstart[n + 1];
  int deg = t - s;
  int tid = threadIdx.x;
  int nload = deg < MAXD ? deg : MAXD;
  if (tid < nload) eid[tid] = elist[s + tid];
  __syncthreads();
  if (tid < nload) {
    int v = eid[tid], r = 0;
    for (int j = 0; j < nload; ++j) r += (eid[j] < v);
    sorted[r] = v;
  }
  __syncthreads();
  if (tid < nload) esrc[tid] = src[sorted[tid]];
  __syncthreads();
  float acc = 0.f;
  for (int k = 0; k < nload; ++k) {
    int e = sorted[k];
    acc += sigf(ehat[(long)e * 128 + tid]) * Bh[(long)esrc[k] * 128 + tid];
  }
  for (int k = MAXD; k < deg; ++k) {
    int e = elist[s + k];
    acc += sigf(ehat[(long)e * 128 + tid]) * Bh[(long)src[e] * 128 + tid];
  }
  x[(long)n * 128 + tid] += acc;
}

// ---- node BN partials: 250 blocks x 80 rows -> part[blk][256] (no atomics) ----
__global__ __launch_bounds__(256) void stats128p(const float* __restrict__ x, float* __restrict__ part)
{
  __shared__ float red[8][32][8];
  int tid = threadIdx.x, tx = tid & 31, ty = tid >> 5;
  long rbase = (long)blockIdx.x * 80;
  float a0 = 0, a1 = 0, a2 = 0, a3 = 0, c0 = 0, c1 = 0, c2 = 0, c3 = 0;
  #pragma unroll
  for (int i = 0; i < 10; ++i) {
    long row = rbase + i * 8 + ty;
    float4 v = *(const float4*)(x + row * 128 + tx * 4);
    a0 += v.x; a1 += v.y; a2 += v.z; a3 += v.w;
    c0 += v.x * v.x; c1 += v.y * v.y; c2 += v.z * v.z; c3 += v.w * v.w;
  }
  red[ty][tx][0] = a0; red[ty][tx][1] = a1; red[ty][tx][2] = a2; red[ty][tx][3] = a3;
  red[ty][tx][4] = c0; red[ty][tx][5] = c1; red[ty][tx][6] = c2; red[ty][tx][7] = c3;
  __syncthreads();
  if (ty == 0) {
    float b0 = 0, b1 = 0, b2 = 0, b3 = 0, d0 = 0, d1 = 0, d2 = 0, d3 = 0;
    #pragma unroll
    for (int t = 0; t < 8; ++t) {
      b0 += red[t][tx][0]; b1 += red[t][tx][1]; b2 += red[t][tx][2]; b3 += red[t][tx][3];
      d0 += red[t][tx][4]; d1 += red[t][tx][5]; d2 += red[t][tx][6]; d3 += red[t][tx][7];
    }
    float* bp = part + (long)blockIdx.x * 256;
    bp[tx * 4 + 0] = b0; bp[tx * 4 + 1] = b1; bp[tx * 4 + 2] = b2; bp[tx * 4 + 3] = b3;
    bp[128 + tx * 4 + 0] = d0; bp[128 + tx * 4 + 1] = d1;
    bp[128 + tx * 4 + 2] = d2; bp[128 + tx * 4 + 3] = d3;
  }
}

// ---- pass 2 (residual + relu(bn(x))): dsta += max(0, scale*x + shift) ----
__global__ __launch_bounds__(256) void pass2(
    float* __restrict__ dsta, const float* __restrict__ xv,
    const float* __restrict__ scale, const float* __restrict__ shift, long n4)
{
  long i = (long)blockIdx.x * 256 + threadIdx.x;
  if (i >= n4) return;
  int c = (int)(i & 31) * 4;
  float4 x = ((const float4*)xv)[i];
  float4 sc = *(const float4*)(scale + c);
  float4 sh = *(const float4*)(shift + c);
  float4 d = ((const float4*)dsta)[i];
  d.x += fmaxf(fmaf(sc.x, x.x, sh.x), 0.f);
  d.y += fmaxf(fmaf(sc.y, x.y, sh.y), 0.f);
  d.z += fmaxf(fmaf(sc.z, x.z, sh.z), 0.f);
  d.w += fmaxf(fmaf(sc.w, x.w, sh.w), 0.f);
  ((float4*)dsta)[i] = d;
}

// ---- column-sum partials of h: 250 blocks x 80 rows -> hpart[blk][128] ----
__global__ __launch_bounds__(256) void colsum_p(const float* __restrict__ h, float* __restrict__ hpart)
{
  __shared__ float red[8][32][4];
  int tid = threadIdx.x, tx = tid & 31, ty = tid >> 5;
  long rbase = (long)blockIdx.x * 80;
  float a0 = 0, a1 = 0, a2 = 0, a3 = 0;
  #pragma unroll
  for (int i = 0; i < 10; ++i) {
    long row = rbase + i * 8 + ty;
    float4 v = *(const float4*)(h + row * 128 + tx * 4);
    a0 += v.x; a1 += v.y; a2 += v.z; a3 += v.w;
  }
  red[ty][tx][0] = a0; red[ty][tx][1] = a1; red[ty][tx][2] = a2; red[ty][tx][3] = a3;
  __syncthreads();
  if (ty == 0) {
    float b0 = 0, b1 = 0, b2 = 0, b3 = 0;
    #pragma unroll
    for (int t = 0; t < 8; ++t) {
      b0 += red[t][tx][0]; b1 += red[t][tx][1]; b2 += red[t][tx][2]; b3 += red[t][tx][3];
    }
    float* bp = hpart + (long)blockIdx.x * 128;
    bp[tx * 4 + 0] = b0; bp[tx * 4 + 1] = b1; bp[tx * 4 + 2] = b2; bp[tx * 4 + 3] = b3;
  }
}

// ---- classifier head: mean from 250 partials -> relu(W1) -> W2 ----
__global__ void cls_head(const float* __restrict__ hpart,
                         const float* __restrict__ W1, const float* __restrict__ b1,
                         const float* __restrict__ W2, const float* __restrict__ b2,
                         float* __restrict__ out)
{
  __shared__ float hm[128];
  __shared__ float r1[128];
  int t = threadIdx.x;  // 128
  float s = 0.f;
  for (int p = 0; p < 250; ++p) s += hpart[(long)p * 128 + t];
  hm[t] = s * (1.0f / NN);
  __syncthreads();
  float v = b1[t];
  for (int k = 0; k < 128; ++k) v = fmaf(hm[k], W1[k * 128 + t], v);
  r1[t] = fmaxf(v, 0.f);
  __syncthreads();
  if (t < 64) {
    float o = b2[t];
    for (int k = 0; k < 128; ++k) o = fmaf(r1[k], W2[k * 64 + t], o);
    out[t] = o;
  }
}

extern "C" void kernel_launch(void* const* d_in, const int* in_sizes, int n_in,
                              void* d_out, int out_size, void* d_ws, size_t ws_size,
                              hipStream_t stream)
{
  const float* h_in  = (const float*)d_in[0];
  const int*   ei    = (const int*)d_in[1];
  const float* eattr = (const float*)d_in[2];
  const float* nW    = (const float*)d_in[3];
  const float* nb    = (const float*)d_in[4];
  const float* eW    = (const float*)d_in[5];
  const float* eb    = (const float*)d_in[6];
  const float* LW    = (const float*)d_in[7];
  const float* LB    = (const float*)d_in[8];
  const float* G     = (const float*)d_in[9];
  const float* Bt    = (const float*)d_in[10];
  const float* W1    = (const float*)d_in[11];
  const float* b1    = (const float*)d_in[12];
  const float* W2    = (const float*)d_in[13];
  const float* b2    = (const float*)d_in[14];
  float* out = (float*)d_out;

  float* ws = (float*)d_ws;
  float* f_h     = ws;
  float* f_e     = f_h    + (long)NN * 128;
  float* f_ehat  = f_e    + (long)NE * 128;
  float* f_A     = f_ehat + (long)NE * 128;
  float* f_B     = f_A    + (long)NN * 128;
  float* f_D     = f_B    + (long)NN * 128;
  float* f_E     = f_D    + (long)NN * 128;
  float* f_stats = f_E    + (long)NN * 128;           // 512: scale/shift x2
  float* f_npart = f_stats + S_TOTAL;                 // 250*256
  float* f_epart = f_npart + 250 * 256;               // 5000*256
  float* f_epart2= f_epart + (long)5000 * 256;        // 50*256
  float* f_hpart = f_epart2 + 50 * 256;               // 250*128
  int* i_deg      = (int*)(f_hpart + 250 * 128);
  int* i_rowstart = i_deg + NN;
  int* i_cursor   = i_rowstart + NN + 1;
  int* i_elist    = i_cursor + NN;
  size_t pw_off = ((((char*)(i_elist + NE)) - (char*)d_ws) + 15) & ~(size_t)15;
  unsigned short* pw_h = (unsigned short*)((char*)d_ws + pw_off);
  unsigned short* pw_l = pw_h + (long)17 * 16384;
  const int* src = ei;
  const int* dst = ei + NE;

  // ---- weight pre-split ----
  prep_w<<<64, 256, 0, stream>>>(nW, pw_h, pw_l, 1);
  prep_w<<<64, 256, 0, stream>>>(eW, pw_h + 16384, pw_l + 16384, 1);
  prep_w<<<960, 256, 0, stream>>>(LW, pw_h + 2 * 16384, pw_l + 2 * 16384, 15);

  // ---- CSR build ----
  hipMemsetAsync(i_deg, 0, NN * sizeof(int), stream);
  hist_dst<<<(NE + 255) / 256, 256, 0, stream>>>(dst, i_deg);
  scan_deg<<<1, 1024, 0, stream>>>(i_deg, i_rowstart, i_cursor);
  fill_csr<<<(NE + 255) / 256, 256, 0, stream>>>(dst, i_cursor, i_elist);

  // ---- embeddings ----
  gemm128<<<313, 256, 0, stream>>>(h_in, pw_h, pw_l, nb, f_h, NN);
  gemm128<<<5000, 256, 0, stream>>>(eattr, pw_h + 16384, pw_l + 16384, eb, f_e, NE);

  for (int l = 0; l < NL; ++l) {
    const unsigned short* lwh = pw_h + (long)(2 + l * 5) * 16384;
    const unsigned short* lwl = pw_l + (long)(2 + l * 5) * 16384;
    const float* bl = LB + (long)l * 5 * 128;
    int last = (l == NL - 1);

    gemm128_x4<<<dim3(313, 4), 256, 0, stream>>>(f_h, lwh, lwl, bl, f_A, f_B, f_D, f_E, NN);
    edge_fused<<<5000, 256, 0, stream>>>(f_e, lwh + 2 * 16384, lwl + 2 * 16384, bl + 2 * 128,
                                         src, dst, f_D, f_E, f_ehat, f_epart, last ? 0 : 1);
    if (!last) {
      reduce_part<<<50, 256, 0, stream>>>(f_epart, f_epart2, 100);
      finalize_bn_p<<<1, 128, 0, stream>>>(f_epart2, 50, 1.0f / NE,
                                           G + (l * 2 + 1) * 128, Bt + (l * 2 + 1) * 128,
                                           f_stats + S_ESC, f_stats + S_ESH);
    }
    gather_node<<<NN, 128, 0, stream>>>(f_ehat, f_B, src, i_rowstart, i_elist, f_A);
    stats128p<<<250, 256, 0, stream>>>(f_A, f_npart);
    finalize_bn_p<<<1, 128, 0, stream>>>(f_npart, 250, 1.0f / NN,
                                         G + (l * 2 + 0) * 128, Bt + (l * 2 + 0) * 128,
                                         f_stats + S_NSC, f_stats + S_NSH);
    pass2<<<2500, 256, 0, stream>>>(f_h, f_A, f_stats + S_NSC, f_stats + S_NSH, (long)NN * 32);
    if (!last)
      pass2<<<40000, 256, 0, stream>>>(f_e, f_ehat, f_stats + S_ESC, f_stats + S_ESH, (long)NE * 32);
  }

  colsum_p<<<250, 256, 0, stream>>>(f_h, f_hpart);
  cls_head<<<1, 128, 0, stream>>>(f_hpart, W1, b1, W2, b2, out);
}

// Round 7
// 1252.678 us; speedup vs baseline: 3.2202x; 1.0699x over previous
//
#include <hip/hip_runtime.h>
#include <math.h>

#define NN 20000
#define NE 320000
#define NL 3
#define EPSV 1e-5f
#define MAXD 128

// f_stats layout (floats)
#define S_ESC  0
#define S_ESH  128
#define S_NSC  256
#define S_NSH  384
#define S_TOTAL 512

typedef __attribute__((ext_vector_type(8))) short bf16x8;
typedef __attribute__((ext_vector_type(4))) float f32x4;

__device__ __forceinline__ float sigf(float x) { return 1.0f / (1.0f + expf(-x)); }
__device__ __forceinline__ float b2f(unsigned short s) { return __uint_as_float((unsigned)s << 16); }

// round-to-nearest-even split: a ~= h + l (both bf16)
__device__ __forceinline__ void bsplit(float a, unsigned short& h, unsigned short& l)
{
  unsigned u = __float_as_uint(a);
  unsigned rh = (u + 0x7FFFu + ((u >> 16) & 1u)) >> 16;
  h = (unsigned short)rh;
  float hf = __uint_as_float(rh << 16);
  float d = a - hf;
  unsigned v = __float_as_uint(d);
  l = (unsigned short)((v + 0x7FFFu + ((v >> 16) & 1u)) >> 16);
}

// ---- weight pre-split: src fp32 [nmat][k][c] -> dh/dl bf16 [nmat][c][k] (k-transposed) ----
__global__ __launch_bounds__(256) void prep_w(const float* __restrict__ src,
                                              unsigned short* __restrict__ dh,
                                              unsigned short* __restrict__ dl, int nmat)
{
  int idx = blockIdx.x * 256 + threadIdx.x;
  if (idx >= nmat * 16384) return;
  int m = idx >> 14, r = idx & 16383, k = r >> 7, c = r & 127;
  unsigned short h, l;
  bsplit(src[idx], h, l);
  long o = ((long)m << 14) + c * 128 + k;
  dh[o] = h; dl[o] = l;
}

// ---- W-tile staging (shared by all cores): 128x32 bf16 hi+lo into padded LDS ----
__device__ __forceinline__ void stage_w(const unsigned short* __restrict__ Wh_g,
                                        const unsigned short* __restrict__ Wl_g,
                                        int k0, int tid, unsigned short* Wh, unsigned short* Wl)
{
  #pragma unroll
  for (int jj = 0; jj < 2; ++jj) {
    int idx = tid + jj * 256;
    int c = idx >> 2, g = idx & 3;
    *(uint4*)(Wh + c * 40 + g * 8) = *(const uint4*)(Wh_g + ((long)c << 7) + k0 + g * 8);
    *(uint4*)(Wl + c * 40 + g * 8) = *(const uint4*)(Wl_g + ((long)c << 7) + k0 + g * 8);
  }
}

// ---- MFMA fragment compute on staged tiles ----
__device__ __forceinline__ void mfma_frags(int lane, int w, f32x4 acc[4][2],
    const unsigned short* Ah, const unsigned short* Al,
    const unsigned short* Wh, const unsigned short* Wl)
{
  int r16 = lane & 15, g8 = lane >> 4;
  bf16x8 ah[4], al[4], wh[2], wl[2];
  #pragma unroll
  for (int rg = 0; rg < 4; ++rg) {
    ah[rg] = *(const bf16x8*)(Ah + (rg * 16 + r16) * 40 + g8 * 8);
    al[rg] = *(const bf16x8*)(Al + (rg * 16 + r16) * 40 + g8 * 8);
  }
  #pragma unroll
  for (int cg = 0; cg < 2; ++cg) {
    int c = w * 32 + cg * 16 + r16;
    wh[cg] = *(const bf16x8*)(Wh + c * 40 + g8 * 8);
    wl[cg] = *(const bf16x8*)(Wl + c * 40 + g8 * 8);
  }
  #pragma unroll
  for (int rg = 0; rg < 4; ++rg)
    #pragma unroll
    for (int cg = 0; cg < 2; ++cg) {
      acc[rg][cg] = __builtin_amdgcn_mfma_f32_16x16x32_bf16(ah[rg], wh[cg], acc[rg][cg], 0, 0, 0);
      acc[rg][cg] = __builtin_amdgcn_mfma_f32_16x16x32_bf16(ah[rg], wl[cg], acc[rg][cg], 0, 0, 0);
      acc[rg][cg] = __builtin_amdgcn_mfma_f32_16x16x32_bf16(al[rg], wh[cg], acc[rg][cg], 0, 0, 0);
    }
}

// ---- core, fp32 input (bsplit on the fly) ----
__device__ __forceinline__ void mfma_core_f32(
    const float* __restrict__ A, long base, int M,
    const unsigned short* __restrict__ Wh_g, const unsigned short* __restrict__ Wl_g,
    int tid, f32x4 acc[4][2],
    unsigned short* Ah, unsigned short* Al, unsigned short* Wh, unsigned short* Wl)
{
  int lane = tid & 63, w = tid >> 6;
  #pragma unroll
  for (int rg = 0; rg < 4; ++rg)
    #pragma unroll
    for (int cg = 0; cg < 2; ++cg)
      acc[rg][cg] = (f32x4){0.f, 0.f, 0.f, 0.f};

  for (int k0 = 0; k0 < 128; k0 += 32) {
    #pragma unroll
    for (int jj = 0; jj < 2; ++jj) {
      int idx = tid + jj * 256;
      int row = idx >> 3, c4 = idx & 7;
      long grow = base + row;
      float4 v = make_float4(0.f, 0.f, 0.f, 0.f);
      if (grow < M) v = *(const float4*)(A + grow * 128 + k0 + c4 * 4);
      unsigned short h0, l0, h1, l1, h2, l2, h3, l3;
      bsplit(v.x, h0, l0); bsplit(v.y, h1, l1); bsplit(v.z, h2, l2); bsplit(v.w, h3, l3);
      *(uint2*)(Ah + row * 40 + c4 * 4) =
          make_uint2((unsigned)h0 | ((unsigned)h1 << 16), (unsigned)h2 | ((unsigned)h3 << 16));
      *(uint2*)(Al + row * 40 + c4 * 4) =
          make_uint2((unsigned)l0 | ((unsigned)l1 << 16), (unsigned)l2 | ((unsigned)l3 << 16));
    }
    stage_w(Wh_g, Wl_g, k0, tid, Wh, Wl);
    __syncthreads();
    mfma_frags(lane, w, acc, Ah, Al, Wh, Wl);
    __syncthreads();
  }
}

// ---- core, pre-split bf16 input (no VALU staging) ----
__device__ __forceinline__ void mfma_core_split(
    const unsigned short* __restrict__ Ahi, const unsigned short* __restrict__ Alo, long base,
    const unsigned short* __restrict__ Wh_g, const unsigned short* __restrict__ Wl_g,
    int tid, f32x4 acc[4][2],
    unsigned short* Ah, unsigned short* Al, unsigned short* Wh, unsigned short* Wl)
{
  int lane = tid & 63, w = tid >> 6;
  #pragma unroll
  for (int rg = 0; rg < 4; ++rg)
    #pragma unroll
    for (int cg = 0; cg < 2; ++cg)
      acc[rg][cg] = (f32x4){0.f, 0.f, 0.f, 0.f};

  int row = tid >> 2, q = tid & 3;
  for (int k0 = 0; k0 < 128; k0 += 32) {
    long gof = (base + row) * 128 + k0 + q * 8;
    *(uint4*)(Ah + row * 40 + q * 8) = *(const uint4*)(Ahi + gof);
    *(uint4*)(Al + row * 40 + q * 8) = *(const uint4*)(Alo + gof);
    stage_w(Wh_g, Wl_g, k0, tid, Wh, Wl);
    __syncthreads();
    mfma_frags(lane, w, acc, Ah, Al, Wh, Wl);
    __syncthreads();
  }
}

// ---- core, fused edge update: e_new = (hi+lo) + relu(sc*ehat + sh); optional write-back ----
template<bool WB>
__device__ __forceinline__ void mfma_core_upd(
    unsigned short* __restrict__ Ahi, unsigned short* __restrict__ Alo,
    const float* __restrict__ EHAT, long base,
    const unsigned short* __restrict__ Wh_g, const unsigned short* __restrict__ Wl_g,
    const float* s_sc, const float* s_sh,
    int tid, f32x4 acc[4][2],
    unsigned short* Ah, unsigned short* Al, unsigned short* Wh, unsigned short* Wl)
{
  int lane = tid & 63, w = tid >> 6;
  #pragma unroll
  for (int rg = 0; rg < 4; ++rg)
    #pragma unroll
    for (int cg = 0; cg < 2; ++cg)
      acc[rg][cg] = (f32x4){0.f, 0.f, 0.f, 0.f};

  int row = tid >> 2, q = tid & 3;
  for (int k0 = 0; k0 < 128; k0 += 32) {
    int cb = k0 + q * 8;
    long gof = (base + row) * 128 + cb;
    uint4 hv = *(const uint4*)(Ahi + gof);
    uint4 lv = *(const uint4*)(Alo + gof);
    float4 e0 = *(const float4*)(EHAT + gof);
    float4 e1 = *(const float4*)(EHAT + gof + 4);
    float eh[8] = {e0.x, e0.y, e0.z, e0.w, e1.x, e1.y, e1.z, e1.w};
    unsigned hs[8] = {hv.x & 0xFFFFu, hv.x >> 16, hv.y & 0xFFFFu, hv.y >> 16,
                      hv.z & 0xFFFFu, hv.z >> 16, hv.w & 0xFFFFu, hv.w >> 16};
    unsigned ls[8] = {lv.x & 0xFFFFu, lv.x >> 16, lv.y & 0xFFFFu, lv.y >> 16,
                      lv.z & 0xFFFFu, lv.z >> 16, lv.w & 0xFFFFu, lv.w >> 16};
    unsigned short nh[8], nl[8];
    #pragma unroll
    for (int i = 0; i < 8; ++i) {
      float v = b2f((unsigned short)hs[i]) + b2f((unsigned short)ls[i]) +
                fmaxf(fmaf(s_sc[cb + i], eh[i], s_sh[cb + i]), 0.f);
      bsplit(v, nh[i], nl[i]);
    }
    uint4 hq = make_uint4((unsigned)nh[0] | ((unsigned)nh[1] << 16),
                          (unsigned)nh[2] | ((unsigned)nh[3] << 16),
                          (unsigned)nh[4] | ((unsigned)nh[5] << 16),
                          (unsigned)nh[6] | ((unsigned)nh[7] << 16));
    uint4 lq = make_uint4((unsigned)nl[0] | ((unsigned)nl[1] << 16),
                          (unsigned)nl[2] | ((unsigned)nl[3] << 16),
                          (unsigned)nl[4] | ((unsigned)nl[5] << 16),
                          (unsigned)nl[6] | ((unsigned)nl[7] << 16));
    *(uint4*)(Ah + row * 40 + q * 8) = hq;
    *(uint4*)(Al + row * 40 + q * 8) = lq;
    if (WB) {
      *(uint4*)(Ahi + gof) = hq;
      *(uint4*)(Alo + gof) = lq;
    }
    stage_w(Wh_g, Wl_g, k0, tid, Wh, Wl);
    __syncthreads();
    mfma_frags(lane, w, acc, Ah, Al, Wh, Wl);
    __syncthreads();
  }
}

// ---- shared edge epilogue: e_hat = Ce+b+Dh[dst]+Eh[src]; store + BN partials ----
__device__ __forceinline__ void edge_epilogue(
    f32x4 acc[4][2], const float* __restrict__ bias,
    const int* __restrict__ src, const int* __restrict__ dst,
    const float* __restrict__ Dh, const float* __restrict__ Eh,
    float* __restrict__ ehat, float* __restrict__ epart, int do_stats,
    long base, int tid)
{
  int lane = tid & 63, w = tid >> 6;
  int r16 = lane & 15, g8 = lane >> 4;
  int colA = w * 32 + r16, colB = colA + 16;
  float bA = bias[colA], bB = bias[colB];
  float s0 = 0.f, s1 = 0.f, q0 = 0.f, q1 = 0.f;
  #pragma unroll
  for (int rg = 0; rg < 4; ++rg)
    #pragma unroll
    for (int j = 0; j < 4; ++j) {
      long erow = base + rg * 16 + g8 * 4 + j;  // NE multiple of 64
      int si = src[erow], di = dst[erow];
      const float* dhp = Dh + (long)di * 128;
      const float* ehp = Eh + (long)si * 128;
      float xA = acc[rg][0][j] + bA + dhp[colA] + ehp[colA];
      float xB = acc[rg][1][j] + bB + dhp[colB] + ehp[colB];
      ehat[erow * 128 + colA] = xA;
      ehat[erow * 128 + colB] = xB;
      s0 += xA; q0 += xA * xA; s1 += xB; q1 += xB * xB;
    }
  if (do_stats) {
    s0 += __shfl_xor(s0, 16); s0 += __shfl_xor(s0, 32);
    q0 += __shfl_xor(q0, 16); q0 += __shfl_xor(q0, 32);
    s1 += __shfl_xor(s1, 16); s1 += __shfl_xor(s1, 32);
    q1 += __shfl_xor(q1, 16); q1 += __shfl_xor(q1, 32);
    if (g8 == 0) {
      float* bp = epart + (long)blockIdx.x * 256;
      bp[colA] = s0;       bp[128 + colA] = q0;
      bp[colB] = s1;       bp[128 + colB] = q1;
    }
  }
}

// ---- C[M,128] = A @ W + b (fp32 out) ----
__global__ __launch_bounds__(256) void gemm128(
    const float* __restrict__ A, const unsigned short* __restrict__ Wh_g,
    const unsigned short* __restrict__ Wl_g, const float* __restrict__ bias,
    float* __restrict__ C, int M)
{
  __shared__ unsigned short Ah[64 * 40], Al[64 * 40], Wh[128 * 40], Wl[128 * 40];
  int tid = threadIdx.x, lane = tid & 63, w = tid >> 6;
  int r16 = lane & 15, g8 = lane >> 4;
  long base = (long)blockIdx.x * 64;
  f32x4 acc[4][2];
  mfma_core_f32(A, base, M, Wh_g, Wl_g, tid, acc, Ah, Al, Wh, Wl);
  #pragma unroll
  for (int cg = 0; cg < 2; ++cg) {
    int col = w * 32 + cg * 16 + r16;
    float b = bias[col];
    #pragma unroll
    for (int rg = 0; rg < 4; ++rg)
      #pragma unroll
      for (int j = 0; j < 4; ++j) {
        long row = base + rg * 16 + g8 * 4 + j;
        if (row < M) C[row * 128 + col] = acc[rg][cg][j] + b;
      }
  }
}

// ---- C = A @ W + b, split-bf16 out (for e embedding) ----
__global__ __launch_bounds__(256) void gemm128s(
    const float* __restrict__ A, const unsigned short* __restrict__ Wh_g,
    const unsigned short* __restrict__ Wl_g, const float* __restrict__ bias,
    unsigned short* __restrict__ Chi, unsigned short* __restrict__ Clo, int M)
{
  __shared__ unsigned short Ah[64 * 40], Al[64 * 40], Wh[128 * 40], Wl[128 * 40];
  int tid = threadIdx.x, lane = tid & 63, w = tid >> 6;
  int r16 = lane & 15, g8 = lane >> 4;
  long base = (long)blockIdx.x * 64;
  f32x4 acc[4][2];
  mfma_core_f32(A, base, M, Wh_g, Wl_g, tid, acc, Ah, Al, Wh, Wl);
  #pragma unroll
  for (int cg = 0; cg < 2; ++cg) {
    int col = w * 32 + cg * 16 + r16;
    float b = bias[col];
    #pragma unroll
    for (int rg = 0; rg < 4; ++rg)
      #pragma unroll
      for (int j = 0; j < 4; ++j) {
        long row = base + rg * 16 + g8 * 4 + j;
        if (row < M) {
          unsigned short hh, ll;
          bsplit(acc[rg][cg][j] + b, hh, ll);
          Chi[row * 128 + col] = hh;
          Clo[row * 128 + col] = ll;
        }
      }
  }
}

// ---- 4 node GEMMs (A,B,D,E) in one launch ----
__global__ __launch_bounds__(256) void gemm128_x4(
    const float* __restrict__ A, const unsigned short* __restrict__ Wh_l,
    const unsigned short* __restrict__ Wl_l, const float* __restrict__ bl,
    float* __restrict__ o0, float* __restrict__ o1, float* __restrict__ o2,
    float* __restrict__ o3, int M)
{
  __shared__ unsigned short Ah[64 * 40], Al[64 * 40], Wh[128 * 40], Wl[128 * 40];
  int y = blockIdx.y;
  int widx = (y < 2) ? y : y + 1;  // {0,1,3,4}
  const unsigned short* Wh_g = Wh_l + ((long)widx << 14);
  const unsigned short* Wl_g = Wl_l + ((long)widx << 14);
  const float* bias = bl + (long)widx * 128;
  float* C = (y == 0) ? o0 : (y == 1) ? o1 : (y == 2) ? o2 : o3;
  int tid = threadIdx.x, lane = tid & 63, w = tid >> 6;
  int r16 = lane & 15, g8 = lane >> 4;
  long base = (long)blockIdx.x * 64;
  f32x4 acc[4][2];
  mfma_core_f32(A, base, M, Wh_g, Wl_g, tid, acc, Ah, Al, Wh, Wl);
  #pragma unroll
  for (int cg = 0; cg < 2; ++cg) {
    int col = w * 32 + cg * 16 + r16;
    float b = bias[col];
    #pragma unroll
    for (int rg = 0; rg < 4; ++rg)
      #pragma unroll
      for (int j = 0; j < 4; ++j) {
        long row = base + rg * 16 + g8 * 4 + j;
        if (row < M) C[row * 128 + col] = acc[rg][cg][j] + b;
      }
  }
}

// ---- edge_fused layer 0: split-input GEMM + epilogue ----
__global__ __launch_bounds__(256) void edge_fused0(
    const unsigned short* __restrict__ ehi, const unsigned short* __restrict__ elo,
    const unsigned short* __restrict__ Wh_g, const unsigned short* __restrict__ Wl_g,
    const float* __restrict__ bias, const int* __restrict__ src, const int* __restrict__ dst,
    const float* __restrict__ Dh, const float* __restrict__ Eh,
    float* __restrict__ ehat, float* __restrict__ epart, int do_stats)
{
  __shared__ unsigned short Ah[64 * 40], Al[64 * 40], Wh[128 * 40], Wl[128 * 40];
  int tid = threadIdx.x;
  long base = (long)blockIdx.x * 64;
  f32x4 acc[4][2];
  mfma_core_split(ehi, elo, base, Wh_g, Wl_g, tid, acc, Ah, Al, Wh, Wl);
  edge_epilogue(acc, bias, src, dst, Dh, Eh, ehat, epart, do_stats, base, tid);
}

// ---- edge_fused layers 1,2: fused e-update staging + GEMM + epilogue ----
template<bool WB>
__global__ __launch_bounds__(256) void edge_fusedU(
    unsigned short* __restrict__ ehi, unsigned short* __restrict__ elo,
    float* __restrict__ ehat,  // in: ehat_{l-1} (staging), out: ehat_l (epilogue)
    const float* __restrict__ scale, const float* __restrict__ shift,
    const unsigned short* __restrict__ Wh_g, const unsigned short* __restrict__ Wl_g,
    const float* __restrict__ bias, const int* __restrict__ src, const int* __restrict__ dst,
    const float* __restrict__ Dh, const float* __restrict__ Eh,
    float* __restrict__ epart, int do_stats)
{
  __shared__ unsigned short Ah[64 * 40], Al[64 * 40], Wh[128 * 40], Wl[128 * 40];
  __shared__ float s_sc[128], s_sh[128];
  int tid = threadIdx.x;
  if (tid < 128) { s_sc[tid] = scale[tid]; s_sh[tid] = shift[tid]; }
  __syncthreads();
  long base = (long)blockIdx.x * 64;
  f32x4 acc[4][2];
  mfma_core_upd<WB>(ehi, elo, ehat, base, Wh_g, Wl_g, s_sc, s_sh, tid, acc, Ah, Al, Wh, Wl);
  edge_epilogue(acc, bias, src, dst, Dh, Eh, ehat, epart, do_stats, base, tid);
}

// ---- generic partial reduce ----
__global__ __launch_bounds__(256) void reduce_part(const float* __restrict__ in,
                                                   float* __restrict__ outp, int groups)
{
  int t = threadIdx.x;
  long base = (long)blockIdx.x * groups * 256;
  float acc = 0.f;
  for (int i = 0; i < groups; ++i) acc += in[base + i * 256 + t];
  outp[(long)blockIdx.x * 256 + t] = acc;
}

__global__ void finalize_bn_p(const float* __restrict__ part, int np, float invn,
                              const float* __restrict__ gamma, const float* __restrict__ beta,
                              float* __restrict__ scale, float* __restrict__ shift)
{
  int c = threadIdx.x;  // 128
  float s = 0.f, q = 0.f;
  for (int p = 0; p < np; ++p) {
    s += part[(long)p * 256 + c];
    q += part[(long)p * 256 + 128 + c];
  }
  float mu = s * invn;
  float var = q * invn - mu * mu;
  float sc = gamma[c] * rsqrtf(var + EPSV);
  scale[c] = sc;
  shift[c] = beta[c] - sc * mu;
}

// ==================== CSR build (by dst) ====================
__global__ __launch_bounds__(256) void hist_dst(const int* __restrict__ dst, int* __restrict__ deg)
{
  int e = blockIdx.x * 256 + threadIdx.x;
  if (e < NE) atomicAdd(&deg[dst[e]], 1);
}

__global__ __launch_bounds__(1024) void scan_deg(const int* __restrict__ deg,
                                                 int* __restrict__ rowstart, int* __restrict__ cursor)
{
  __shared__ int wsum[16];
  __shared__ int carry;
  int tid = threadIdx.x, lane = tid & 63, wid = tid >> 6;
  if (tid == 0) carry = 0;
  __syncthreads();
  for (int base = 0; base < NN; base += 1024) {
    int i = base + tid;
    int v = (i < NN) ? deg[i] : 0;
    int x = v;
    #pragma unroll
    for (int off = 1; off < 64; off <<= 1) {
      int y = __shfl_up(x, off, 64);
      if (lane >= off) x += y;
    }
    if (lane == 63) wsum[wid] = x;
    __syncthreads();
    int wpref = 0;
    for (int j = 0; j < wid; ++j) wpref += wsum[j];
    int excl = carry + wpref + x - v;
    if (i < NN) { rowstart[i] = excl; cursor[i] = excl; }
    __syncthreads();
    if (tid == 1023) carry = excl + v;
    __syncthreads();
  }
  if (tid == 0) rowstart[NN] = NE;
}

__global__ __launch_bounds__(256) void fill_csr(const int* __restrict__ dst,
                                                int* __restrict__ cursor, int* __restrict__ elist)
{
  int e = blockIdx.x * 256 + threadIdx.x;
  if (e < NE) {
    int p = atomicAdd(&cursor[dst[e]], 1);
    elist[p] = e;
  }
}

// ---- per-node gather ----
__global__ __launch_bounds__(128) void gather_node(
    const float* __restrict__ ehat, const float* __restrict__ Bh, const int* __restrict__ src,
    const int* __restrict__ rowstart, const int* __restrict__ elist,
    float* __restrict__ x)
{
  __shared__ int eid[MAXD];
  __shared__ int sorted[MAXD];
  __shared__ int esrc[MAXD];
  int n = blockIdx.x;
  int s = rowstart[n], t = rowstart[n + 1];
  int deg = t - s;
  int tid = threadIdx.x;
  int nload = deg < MAXD ? deg : MAXD;
  if (tid < nload) eid[tid] = elist[s + tid];
  __syncthreads();
  if (tid < nload) {
    int v = eid[tid], r = 0;
    for (int j = 0; j < nload; ++j) r += (eid[j] < v);
    sorted[r] = v;
  }
  __syncthreads();
  if (tid < nload) esrc[tid] = src[sorted[tid]];
  __syncthreads();
  float acc = 0.f;
  for (int k = 0; k < nload; ++k) {
    int e = sorted[k];
    acc += sigf(ehat[(long)e * 128 + tid]) * Bh[(long)esrc[k] * 128 + tid];
  }
  for (int k = MAXD; k < deg; ++k) {
    int e = elist[s + k];
    acc += sigf(ehat[(long)e * 128 + tid]) * Bh[(long)src[e] * 128 + tid];
  }
  x[(long)n * 128 + tid] += acc;
}

// ---- node BN partials: 250 blocks x 80 rows ----
__global__ __launch_bounds__(256) void stats128p(const float* __restrict__ x, float* __restrict__ part)
{
  __shared__ float red[8][32][8];
  int tid = threadIdx.x, tx = tid & 31, ty = tid >> 5;
  long rbase = (long)blockIdx.x * 80;
  float a0 = 0, a1 = 0, a2 = 0, a3 = 0, c0 = 0, c1 = 0, c2 = 0, c3 = 0;
  #pragma unroll
  for (int i = 0; i < 10; ++i) {
    long row = rbase + i * 8 + ty;
    float4 v = *(const float4*)(x + row * 128 + tx * 4);
    a0 += v.x; a1 += v.y; a2 += v.z; a3 += v.w;
    c0 += v.x * v.x; c1 += v.y * v.y; c2 += v.z * v.z; c3 += v.w * v.w;
  }
  red[ty][tx][0] = a0; red[ty][tx][1] = a1; red[ty][tx][2] = a2; red[ty][tx][3] = a3;
  red[ty][tx][4] = c0; red[ty][tx][5] = c1; red[ty][tx][6] = c2; red[ty][tx][7] = c3;
  __syncthreads();
  if (ty == 0) {
    float b0 = 0, b1 = 0, b2 = 0, b3 = 0, d0 = 0, d1 = 0, d2 = 0, d3 = 0;
    #pragma unroll
    for (int t = 0; t < 8; ++t) {
      b0 += red[t][tx][0]; b1 += red[t][tx][1]; b2 += red[t][tx][2]; b3 += red[t][tx][3];
      d0 += red[t][tx][4]; d1 += red[t][tx][5]; d2 += red[t][tx][6]; d3 += red[t][tx][7];
    }
    float* bp = part + (long)blockIdx.x * 256;
    bp[tx * 4 + 0] = b0; bp[tx * 4 + 1] = b1; bp[tx * 4 + 2] = b2; bp[tx * 4 + 3] = b3;
    bp[128 + tx * 4 + 0] = d0; bp[128 + tx * 4 + 1] = d1;
    bp[128 + tx * 4 + 2] = d2; bp[128 + tx * 4 + 3] = d3;
  }
}

// ---- node pass 2: h += relu(bn(x)) ----
__global__ __launch_bounds__(256) void pass2(
    float* __restrict__ dsta, const float* __restrict__ xv,
    const float* __restrict__ scale, const float* __restrict__ shift, long n4)
{
  long i = (long)blockIdx.x * 256 + threadIdx.x;
  if (i >= n4) return;
  int c = (int)(i & 31) * 4;
  float4 x = ((const float4*)xv)[i];
  float4 sc = *(const float4*)(scale + c);
  float4 sh = *(const float4*)(shift + c);
  float4 d = ((const float4*)dsta)[i];
  d.x += fmaxf(fmaf(sc.x, x.x, sh.x), 0.f);
  d.y += fmaxf(fmaf(sc.y, x.y, sh.y), 0.f);
  d.z += fmaxf(fmaf(sc.z, x.z, sh.z), 0.f);
  d.w += fmaxf(fmaf(sc.w, x.w, sh.w), 0.f);
  ((float4*)dsta)[i] = d;
}

// ---- column-sum partials of h ----
__global__ __launch_bounds__(256) void colsum_p(const float* __restrict__ h, float* __restrict__ hpart)
{
  __shared__ float red[8][32][4];
  int tid = threadIdx.x, tx = tid & 31, ty = tid >> 5;
  long rbase = (long)blockIdx.x * 80;
  float a0 = 0, a1 = 0, a2 = 0, a3 = 0;
  #pragma unroll
  for (int i = 0; i < 10; ++i) {
    long row = rbase + i * 8 + ty;
    float4 v = *(const float4*)(h + row * 128 + tx * 4);
    a0 += v.x; a1 += v.y; a2 += v.z; a3 += v.w;
  }
  red[ty][tx][0] = a0; red[ty][tx][1] = a1; red[ty][tx][2] = a2; red[ty][tx][3] = a3;
  __syncthreads();
  if (ty == 0) {
    float b0 = 0, b1 = 0, b2 = 0, b3 = 0;
    #pragma unroll
    for (int t = 0; t < 8; ++t) {
      b0 += red[t][tx][0]; b1 += red[t][tx][1]; b2 += red[t][tx][2]; b3 += red[t][tx][3];
    }
    float* bp = hpart + (long)blockIdx.x * 128;
    bp[tx * 4 + 0] = b0; bp[tx * 4 + 1] = b1; bp[tx * 4 + 2] = b2; bp[tx * 4 + 3] = b3;
  }
}

__global__ void cls_head(const float* __restrict__ hpart,
                         const float* __restrict__ W1, const float* __restrict__ b1,
                         const float* __restrict__ W2, const float* __restrict__ b2,
                         float* __restrict__ out)
{
  __shared__ float hm[128];
  __shared__ float r1[128];
  int t = threadIdx.x;
  float s = 0.f;
  for (int p = 0; p < 250; ++p) s += hpart[(long)p * 128 + t];
  hm[t] = s * (1.0f / NN);
  __syncthreads();
  float v = b1[t];
  for (int k = 0; k < 128; ++k) v = fmaf(hm[k], W1[k * 128 + t], v);
  r1[t] = fmaxf(v, 0.f);
  __syncthreads();
  if (t < 64) {
    float o = b2[t];
    for (int k = 0; k < 128; ++k) o = fmaf(r1[k], W2[k * 64 + t], o);
    out[t] = o;
  }
}

extern "C" void kernel_launch(void* const* d_in, const int* in_sizes, int n_in,
                              void* d_out, int out_size, void* d_ws, size_t ws_size,
                              hipStream_t stream)
{
  const float* h_in  = (const float*)d_in[0];
  const int*   ei    = (const int*)d_in[1];
  const float* eattr = (const float*)d_in[2];
  const float* nW    = (const float*)d_in[3];
  const float* nb    = (const float*)d_in[4];
  const float* eW    = (const float*)d_in[5];
  const float* eb    = (const float*)d_in[6];
  const float* LW    = (const float*)d_in[7];
  const float* LB    = (const float*)d_in[8];
  const float* G     = (const float*)d_in[9];
  const float* Bt    = (const float*)d_in[10];
  const float* W1    = (const float*)d_in[11];
  const float* b1    = (const float*)d_in[12];
  const float* W2    = (const float*)d_in[13];
  const float* b2    = (const float*)d_in[14];
  float* out = (float*)d_out;

  float* ws = (float*)d_ws;
  float* f_h     = ws;
  float* f_ehat  = f_h    + (long)NN * 128;
  float* f_A     = f_ehat + (long)NE * 128;
  float* f_B     = f_A    + (long)NN * 128;
  float* f_D     = f_B    + (long)NN * 128;
  float* f_E     = f_D    + (long)NN * 128;
  float* f_stats = f_E    + (long)NN * 128;
  float* f_npart = f_stats + S_TOTAL;
  float* f_epart = f_npart + 250 * 256;
  float* f_epart2= f_epart + (long)5000 * 256;
  float* f_hpart = f_epart2 + 50 * 256;
  unsigned short* e_hi = (unsigned short*)(f_hpart + 250 * 128);
  unsigned short* e_lo = e_hi + (long)NE * 128;
  int* i_deg      = (int*)(e_lo + (long)NE * 128);
  int* i_rowstart = i_deg + NN;
  int* i_cursor   = i_rowstart + NN + 1;
  int* i_elist    = i_cursor + NN;
  size_t pw_off = ((((char*)(i_elist + NE)) - (char*)d_ws) + 15) & ~(size_t)15;
  unsigned short* pw_h = (unsigned short*)((char*)d_ws + pw_off);
  unsigned short* pw_l = pw_h + (long)17 * 16384;
  const int* src = ei;
  const int* dst = ei + NE;

  // ---- weight pre-split ----
  prep_w<<<64, 256, 0, stream>>>(nW, pw_h, pw_l, 1);
  prep_w<<<64, 256, 0, stream>>>(eW, pw_h + 16384, pw_l + 16384, 1);
  prep_w<<<960, 256, 0, stream>>>(LW, pw_h + 2 * 16384, pw_l + 2 * 16384, 15);

  // ---- CSR build ----
  hipMemsetAsync(i_deg, 0, NN * sizeof(int), stream);
  hist_dst<<<(NE + 255) / 256, 256, 0, stream>>>(dst, i_deg);
  scan_deg<<<1, 1024, 0, stream>>>(i_deg, i_rowstart, i_cursor);
  fill_csr<<<(NE + 255) / 256, 256, 0, stream>>>(dst, i_cursor, i_elist);

  // ---- embeddings: h fp32, e split-bf16 ----
  gemm128<<<313, 256, 0, stream>>>(h_in, pw_h, pw_l, nb, f_h, NN);
  gemm128s<<<5000, 256, 0, stream>>>(eattr, pw_h + 16384, pw_l + 16384, eb, e_hi, e_lo, NE);

  for (int l = 0; l < NL; ++l) {
    const unsigned short* lwh = pw_h + (long)(2 + l * 5) * 16384;
    const unsigned short* lwl = pw_l + (long)(2 + l * 5) * 16384;
    const float* bl = LB + (long)l * 5 * 128;
    int last = (l == NL - 1);

    gemm128_x4<<<dim3(313, 4), 256, 0, stream>>>(f_h, lwh, lwl, bl, f_A, f_B, f_D, f_E, NN);
    if (l == 0)
      edge_fused0<<<5000, 256, 0, stream>>>(e_hi, e_lo, lwh + 2 * 16384, lwl + 2 * 16384,
                                            bl + 2 * 128, src, dst, f_D, f_E,
                                            f_ehat, f_epart, 1);
    else if (l == 1)
      edge_fusedU<true><<<5000, 256, 0, stream>>>(e_hi, e_lo, f_ehat,
                                                  f_stats + S_ESC, f_stats + S_ESH,
                                                  lwh + 2 * 16384, lwl + 2 * 16384, bl + 2 * 128,
                                                  src, dst, f_D, f_E, f_epart, 1);
    else
      edge_fusedU<false><<<5000, 256, 0, stream>>>(e_hi, e_lo, f_ehat,
                                                   f_stats + S_ESC, f_stats + S_ESH,
                                                   lwh + 2 * 16384, lwl + 2 * 16384, bl + 2 * 128,
                                                   src, dst, f_D, f_E, f_epart, 0);
    if (!last) {
      reduce_part<<<50, 256, 0, stream>>>(f_epart, f_epart2, 100);
      finalize_bn_p<<<1, 128, 0, stream>>>(f_epart2, 50, 1.0f / NE,
                                           G + (l * 2 + 1) * 128, Bt + (l * 2 + 1) * 128,
                                           f_stats + S_ESC, f_stats + S_ESH);
    }
    gather_node<<<NN, 128, 0, stream>>>(f_ehat, f_B, src, i_rowstart, i_elist, f_A);
    stats128p<<<250, 256, 0, stream>>>(f_A, f_npart);
    finalize_bn_p<<<1, 128, 0, stream>>>(f_npart, 250, 1.0f / NN,
                                         G + (l * 2 + 0) * 128, Bt + (l * 2 + 0) * 128,
                                         f_stats + S_NSC, f_stats + S_NSH);
    pass2<<<2500, 256, 0, stream>>>(f_h, f_A, f_stats + S_NSC, f_stats + S_NSH, (long)NN * 32);
    // edge residual now fused into next layer's edge_fusedU staging
  }

  colsum_p<<<250, 256, 0, stream>>>(f_h, f_hpart);
  cls_head<<<1, 128, 0, stream>>>(f_hpart, W1, b1, W2, b2, out);
}

// Round 8
// 1210.352 us; speedup vs baseline: 3.3328x; 1.0350x over previous
//
#include <hip/hip_runtime.h>
#include <math.h>

#define NN 20000
#define NE 320000
#define NL 3
#define EPSV 1e-5f
#define MAXD 128

// f_stats layout (floats)
#define S_ESC  0
#define S_ESH  128
#define S_NSC  256
#define S_NSH  384
#define S_TOTAL 512

typedef __attribute__((ext_vector_type(8))) short bf16x8;
typedef __attribute__((ext_vector_type(4))) float f32x4;

__device__ __forceinline__ float sigf(float x) { return 1.0f / (1.0f + expf(-x)); }
__device__ __forceinline__ float b2f(unsigned short s) { return __uint_as_float((unsigned)s << 16); }

// round-to-nearest-even split: a ~= h + l (both bf16)
__device__ __forceinline__ void bsplit(float a, unsigned short& h, unsigned short& l)
{
  unsigned u = __float_as_uint(a);
  unsigned rh = (u + 0x7FFFu + ((u >> 16) & 1u)) >> 16;
  h = (unsigned short)rh;
  float hf = __uint_as_float(rh << 16);
  float d = a - hf;
  unsigned v = __float_as_uint(d);
  l = (unsigned short)((v + 0x7FFFu + ((v >> 16) & 1u)) >> 16);
}

// ---- weight pre-split: src fp32 [nmat][k][c] -> dh/dl bf16 [nmat][c][k] (k-transposed) ----
__global__ __launch_bounds__(256) void prep_w(const float* __restrict__ src,
                                              unsigned short* __restrict__ dh,
                                              unsigned short* __restrict__ dl, int nmat)
{
  int idx = blockIdx.x * 256 + threadIdx.x;
  if (idx >= nmat * 16384) return;
  int m = idx >> 14, r = idx & 16383, k = r >> 7, c = r & 127;
  unsigned short h, l;
  bsplit(src[idx], h, l);
  long o = ((long)m << 14) + c * 128 + k;
  dh[o] = h; dl[o] = l;
}

// ---- W-tile staging: 128x32 bf16 hi+lo into padded LDS ----
__device__ __forceinline__ void stage_w(const unsigned short* __restrict__ Wh_g,
                                        const unsigned short* __restrict__ Wl_g,
                                        int k0, int tid, unsigned short* Wh, unsigned short* Wl)
{
  #pragma unroll
  for (int jj = 0; jj < 2; ++jj) {
    int idx = tid + jj * 256;
    int c = idx >> 2, g = idx & 3;
    *(uint4*)(Wh + c * 40 + g * 8) = *(const uint4*)(Wh_g + ((long)c << 7) + k0 + g * 8);
    *(uint4*)(Wl + c * 40 + g * 8) = *(const uint4*)(Wl_g + ((long)c << 7) + k0 + g * 8);
  }
}

// ---- MFMA fragment compute on staged tiles ----
__device__ __forceinline__ void mfma_frags(int lane, int w, f32x4 acc[4][2],
    const unsigned short* Ah, const unsigned short* Al,
    const unsigned short* Wh, const unsigned short* Wl)
{
  int r16 = lane & 15, g8 = lane >> 4;
  bf16x8 ah[4], al[4], wh[2], wl[2];
  #pragma unroll
  for (int rg = 0; rg < 4; ++rg) {
    ah[rg] = *(const bf16x8*)(Ah + (rg * 16 + r16) * 40 + g8 * 8);
    al[rg] = *(const bf16x8*)(Al + (rg * 16 + r16) * 40 + g8 * 8);
  }
  #pragma unroll
  for (int cg = 0; cg < 2; ++cg) {
    int c = w * 32 + cg * 16 + r16;
    wh[cg] = *(const bf16x8*)(Wh + c * 40 + g8 * 8);
    wl[cg] = *(const bf16x8*)(Wl + c * 40 + g8 * 8);
  }
  #pragma unroll
  for (int rg = 0; rg < 4; ++rg)
    #pragma unroll
    for (int cg = 0; cg < 2; ++cg) {
      acc[rg][cg] = __builtin_amdgcn_mfma_f32_16x16x32_bf16(ah[rg], wh[cg], acc[rg][cg], 0, 0, 0);
      acc[rg][cg] = __builtin_amdgcn_mfma_f32_16x16x32_bf16(ah[rg], wl[cg], acc[rg][cg], 0, 0, 0);
      acc[rg][cg] = __builtin_amdgcn_mfma_f32_16x16x32_bf16(al[rg], wh[cg], acc[rg][cg], 0, 0, 0);
    }
}

// ---- core, fp32 input (bsplit on the fly), direct rows ----
__device__ __forceinline__ void mfma_core_f32(
    const float* __restrict__ A, long base, int M,
    const unsigned short* __restrict__ Wh_g, const unsigned short* __restrict__ Wl_g,
    int tid, f32x4 acc[4][2],
    unsigned short* Ah, unsigned short* Al, unsigned short* Wh, unsigned short* Wl)
{
  int lane = tid & 63, w = tid >> 6;
  #pragma unroll
  for (int rg = 0; rg < 4; ++rg)
    #pragma unroll
    for (int cg = 0; cg < 2; ++cg)
      acc[rg][cg] = (f32x4){0.f, 0.f, 0.f, 0.f};

  for (int k0 = 0; k0 < 128; k0 += 32) {
    #pragma unroll
    for (int jj = 0; jj < 2; ++jj) {
      int idx = tid + jj * 256;
      int row = idx >> 3, c4 = idx & 7;
      long grow = base + row;
      float4 v = make_float4(0.f, 0.f, 0.f, 0.f);
      if (grow < M) v = *(const float4*)(A + grow * 128 + k0 + c4 * 4);
      unsigned short h0, l0, h1, l1, h2, l2, h3, l3;
      bsplit(v.x, h0, l0); bsplit(v.y, h1, l1); bsplit(v.z, h2, l2); bsplit(v.w, h3, l3);
      *(uint2*)(Ah + row * 40 + c4 * 4) =
          make_uint2((unsigned)h0 | ((unsigned)h1 << 16), (unsigned)h2 | ((unsigned)h3 << 16));
      *(uint2*)(Al + row * 40 + c4 * 4) =
          make_uint2((unsigned)l0 | ((unsigned)l1 << 16), (unsigned)l2 | ((unsigned)l3 << 16));
    }
    stage_w(Wh_g, Wl_g, k0, tid, Wh, Wl);
    __syncthreads();
    mfma_frags(lane, w, acc, Ah, Al, Wh, Wl);
    __syncthreads();
  }
}

// ---- core, fp32 input with LDS row-index indirection (rows always valid) ----
__device__ __forceinline__ void mfma_core_f32i(
    const float* __restrict__ A, const int* ridx,
    const unsigned short* __restrict__ Wh_g, const unsigned short* __restrict__ Wl_g,
    int tid, f32x4 acc[4][2],
    unsigned short* Ah, unsigned short* Al, unsigned short* Wh, unsigned short* Wl)
{
  int lane = tid & 63, w = tid >> 6;
  #pragma unroll
  for (int rg = 0; rg < 4; ++rg)
    #pragma unroll
    for (int cg = 0; cg < 2; ++cg)
      acc[rg][cg] = (f32x4){0.f, 0.f, 0.f, 0.f};

  for (int k0 = 0; k0 < 128; k0 += 32) {
    #pragma unroll
    for (int jj = 0; jj < 2; ++jj) {
      int idx = tid + jj * 256;
      int row = idx >> 3, c4 = idx & 7;
      long grow = ridx[row];
      float4 v = *(const float4*)(A + grow * 128 + k0 + c4 * 4);
      unsigned short h0, l0, h1, l1, h2, l2, h3, l3;
      bsplit(v.x, h0, l0); bsplit(v.y, h1, l1); bsplit(v.z, h2, l2); bsplit(v.w, h3, l3);
      *(uint2*)(Ah + row * 40 + c4 * 4) =
          make_uint2((unsigned)h0 | ((unsigned)h1 << 16), (unsigned)h2 | ((unsigned)h3 << 16));
      *(uint2*)(Al + row * 40 + c4 * 4) =
          make_uint2((unsigned)l0 | ((unsigned)l1 << 16), (unsigned)l2 | ((unsigned)l3 << 16));
    }
    stage_w(Wh_g, Wl_g, k0, tid, Wh, Wl);
    __syncthreads();
    mfma_frags(lane, w, acc, Ah, Al, Wh, Wl);
    __syncthreads();
  }
}

// ---- core, pre-split bf16 input ----
__device__ __forceinline__ void mfma_core_split(
    const unsigned short* __restrict__ Ahi, const unsigned short* __restrict__ Alo, long base,
    const unsigned short* __restrict__ Wh_g, const unsigned short* __restrict__ Wl_g,
    int tid, f32x4 acc[4][2],
    unsigned short* Ah, unsigned short* Al, unsigned short* Wh, unsigned short* Wl)
{
  int lane = tid & 63, w = tid >> 6;
  #pragma unroll
  for (int rg = 0; rg < 4; ++rg)
    #pragma unroll
    for (int cg = 0; cg < 2; ++cg)
      acc[rg][cg] = (f32x4){0.f, 0.f, 0.f, 0.f};

  int row = tid >> 2, q = tid & 3;
  for (int k0 = 0; k0 < 128; k0 += 32) {
    long gof = (base + row) * 128 + k0 + q * 8;
    *(uint4*)(Ah + row * 40 + q * 8) = *(const uint4*)(Ahi + gof);
    *(uint4*)(Al + row * 40 + q * 8) = *(const uint4*)(Alo + gof);
    stage_w(Wh_g, Wl_g, k0, tid, Wh, Wl);
    __syncthreads();
    mfma_frags(lane, w, acc, Ah, Al, Wh, Wl);
    __syncthreads();
  }
}

// ---- core, fused edge update: e_new = (hi+lo) + relu(sc*ehat + sh); optional write-back ----
template<bool WB>
__device__ __forceinline__ void mfma_core_upd(
    unsigned short* __restrict__ Ahi, unsigned short* __restrict__ Alo,
    const float* __restrict__ EHAT, long base,
    const unsigned short* __restrict__ Wh_g, const unsigned short* __restrict__ Wl_g,
    const float* s_sc, const float* s_sh,
    int tid, f32x4 acc[4][2],
    unsigned short* Ah, unsigned short* Al, unsigned short* Wh, unsigned short* Wl)
{
  int lane = tid & 63, w = tid >> 6;
  #pragma unroll
  for (int rg = 0; rg < 4; ++rg)
    #pragma unroll
    for (int cg = 0; cg < 2; ++cg)
      acc[rg][cg] = (f32x4){0.f, 0.f, 0.f, 0.f};

  int row = tid >> 2, q = tid & 3;
  for (int k0 = 0; k0 < 128; k0 += 32) {
    int cb = k0 + q * 8;
    long gof = (base + row) * 128 + cb;
    uint4 hv = *(const uint4*)(Ahi + gof);
    uint4 lv = *(const uint4*)(Alo + gof);
    float4 e0 = *(const float4*)(EHAT + gof);
    float4 e1 = *(const float4*)(EHAT + gof + 4);
    float eh[8] = {e0.x, e0.y, e0.z, e0.w, e1.x, e1.y, e1.z, e1.w};
    unsigned hs[8] = {hv.x & 0xFFFFu, hv.x >> 16, hv.y & 0xFFFFu, hv.y >> 16,
                      hv.z & 0xFFFFu, hv.z >> 16, hv.w & 0xFFFFu, hv.w >> 16};
    unsigned ls[8] = {lv.x & 0xFFFFu, lv.x >> 16, lv.y & 0xFFFFu, lv.y >> 16,
                      lv.z & 0xFFFFu, lv.z >> 16, lv.w & 0xFFFFu, lv.w >> 16};
    unsigned short nh[8], nl[8];
    #pragma unroll
    for (int i = 0; i < 8; ++i) {
      float v = b2f((unsigned short)hs[i]) + b2f((unsigned short)ls[i]) +
                fmaxf(fmaf(s_sc[cb + i], eh[i], s_sh[cb + i]), 0.f);
      bsplit(v, nh[i], nl[i]);
    }
    uint4 hq = make_uint4((unsigned)nh[0] | ((unsigned)nh[1] << 16),
                          (unsigned)nh[2] | ((unsigned)nh[3] << 16),
                          (unsigned)nh[4] | ((unsigned)nh[5] << 16),
                          (unsigned)nh[6] | ((unsigned)nh[7] << 16));
    uint4 lq = make_uint4((unsigned)nl[0] | ((unsigned)nl[1] << 16),
                          (unsigned)nl[2] | ((unsigned)nl[3] << 16),
                          (unsigned)nl[4] | ((unsigned)nl[5] << 16),
                          (unsigned)nl[6] | ((unsigned)nl[7] << 16));
    *(uint4*)(Ah + row * 40 + q * 8) = hq;
    *(uint4*)(Al + row * 40 + q * 8) = lq;
    if (WB) {
      *(uint4*)(Ahi + gof) = hq;
      *(uint4*)(Alo + gof) = lq;
    }
    stage_w(Wh_g, Wl_g, k0, tid, Wh, Wl);
    __syncthreads();
    mfma_frags(lane, w, acc, Ah, Al, Wh, Wl);
    __syncthreads();
  }
}

// ---- shared edge epilogue: e_hat = Ce+b+Dh[dst]+Eh[src]; store + BN partials ----
__device__ __forceinline__ void edge_epilogue(
    f32x4 acc[4][2], const float* __restrict__ bias,
    const int* __restrict__ srcp, const int* __restrict__ dstp,
    const float* __restrict__ Dh, const float* __restrict__ Eh,
    float* __restrict__ ehat, float* __restrict__ epart, int do_stats,
    long base, int tid)
{
  int lane = tid & 63, w = tid >> 6;
  int r16 = lane & 15, g8 = lane >> 4;
  int colA = w * 32 + r16, colB = colA + 16;
  float bA = bias[colA], bB = bias[colB];
  float s0 = 0.f, s1 = 0.f, q0 = 0.f, q1 = 0.f;
  #pragma unroll
  for (int rg = 0; rg < 4; ++rg)
    #pragma unroll
    for (int j = 0; j < 4; ++j) {
      long erow = base + rg * 16 + g8 * 4 + j;  // NE multiple of 64
      int si = srcp[erow], di = dstp[erow];
      const float* dhp = Dh + (long)di * 128;
      const float* ehp = Eh + (long)si * 128;
      float xA = acc[rg][0][j] + bA + dhp[colA] + ehp[colA];
      float xB = acc[rg][1][j] + bB + dhp[colB] + ehp[colB];
      ehat[erow * 128 + colA] = xA;
      ehat[erow * 128 + colB] = xB;
      s0 += xA; q0 += xA * xA; s1 += xB; q1 += xB * xB;
    }
  if (do_stats) {
    s0 += __shfl_xor(s0, 16); s0 += __shfl_xor(s0, 32);
    q0 += __shfl_xor(q0, 16); q0 += __shfl_xor(q0, 32);
    s1 += __shfl_xor(s1, 16); s1 += __shfl_xor(s1, 32);
    q1 += __shfl_xor(q1, 16); q1 += __shfl_xor(q1, 32);
    if (g8 == 0) {
      float* bp = epart + (long)blockIdx.x * 256;
      bp[colA] = s0;       bp[128 + colA] = q0;
      bp[colB] = s1;       bp[128 + colB] = q1;
    }
  }
}

// ---- C[M,128] = A @ W + b (fp32 out) ----
__global__ __launch_bounds__(256) void gemm128(
    const float* __restrict__ A, const unsigned short* __restrict__ Wh_g,
    const unsigned short* __restrict__ Wl_g, const float* __restrict__ bias,
    float* __restrict__ C, int M)
{
  __shared__ unsigned short Ah[64 * 40], Al[64 * 40], Wh[128 * 40], Wl[128 * 40];
  int tid = threadIdx.x, lane = tid & 63, w = tid >> 6;
  int r16 = lane & 15, g8 = lane >> 4;
  long base = (long)blockIdx.x * 64;
  f32x4 acc[4][2];
  mfma_core_f32(A, base, M, Wh_g, Wl_g, tid, acc, Ah, Al, Wh, Wl);
  #pragma unroll
  for (int cg = 0; cg < 2; ++cg) {
    int col = w * 32 + cg * 16 + r16;
    float b = bias[col];
    #pragma unroll
    for (int rg = 0; rg < 4; ++rg)
      #pragma unroll
      for (int j = 0; j < 4; ++j) {
        long row = base + rg * 16 + g8 * 4 + j;
        if (row < M) C[row * 128 + col] = acc[rg][cg][j] + b;
      }
  }
}

// ---- e embedding: rows of A via elist indirection; split-bf16 out (slot space) ----
__global__ __launch_bounds__(256) void gemm128s(
    const float* __restrict__ A, const int* __restrict__ rows,
    const unsigned short* __restrict__ Wh_g, const unsigned short* __restrict__ Wl_g,
    const float* __restrict__ bias,
    unsigned short* __restrict__ Chi, unsigned short* __restrict__ Clo)
{
  __shared__ unsigned short Ah[64 * 40], Al[64 * 40], Wh[128 * 40], Wl[128 * 40];
  __shared__ int ridx[64];
  int tid = threadIdx.x, lane = tid & 63, w = tid >> 6;
  int r16 = lane & 15, g8 = lane >> 4;
  long base = (long)blockIdx.x * 64;
  if (tid < 64) ridx[tid] = rows[base + tid];
  __syncthreads();
  f32x4 acc[4][2];
  mfma_core_f32i(A, ridx, Wh_g, Wl_g, tid, acc, Ah, Al, Wh, Wl);
  #pragma unroll
  for (int cg = 0; cg < 2; ++cg) {
    int col = w * 32 + cg * 16 + r16;
    float b = bias[col];
    #pragma unroll
    for (int rg = 0; rg < 4; ++rg)
      #pragma unroll
      for (int j = 0; j < 4; ++j) {
        long row = base + rg * 16 + g8 * 4 + j;
        unsigned short hh, ll;
        bsplit(acc[rg][cg][j] + b, hh, ll);
        Chi[row * 128 + col] = hh;
        Clo[row * 128 + col] = ll;
      }
  }
}

// ---- 4 node GEMMs (A,B,D,E) in one launch ----
__global__ __launch_bounds__(256) void gemm128_x4(
    const float* __restrict__ A, const unsigned short* __restrict__ Wh_l,
    const unsigned short* __restrict__ Wl_l, const float* __restrict__ bl,
    float* __restrict__ o0, float* __restrict__ o1, float* __restrict__ o2,
    float* __restrict__ o3, int M)
{
  __shared__ unsigned short Ah[64 * 40], Al[64 * 40], Wh[128 * 40], Wl[128 * 40];
  int y = blockIdx.y;
  int widx = (y < 2) ? y : y + 1;  // {0,1,3,4}
  const unsigned short* Wh_g = Wh_l + ((long)widx << 14);
  const unsigned short* Wl_g = Wl_l + ((long)widx << 14);
  const float* bias = bl + (long)widx * 128;
  float* C = (y == 0) ? o0 : (y == 1) ? o1 : (y == 2) ? o2 : o3;
  int tid = threadIdx.x, lane = tid & 63, w = tid >> 6;
  int r16 = lane & 15, g8 = lane >> 4;
  long base = (long)blockIdx.x * 64;
  f32x4 acc[4][2];
  mfma_core_f32(A, base, M, Wh_g, Wl_g, tid, acc, Ah, Al, Wh, Wl);
  #pragma unroll
  for (int cg = 0; cg < 2; ++cg) {
    int col = w * 32 + cg * 16 + r16;
    float b = bias[col];
    #pragma unroll
    for (int rg = 0; rg < 4; ++rg)
      #pragma unroll
      for (int j = 0; j < 4; ++j) {
        long row = base + rg * 16 + g8 * 4 + j;
        if (row < M) C[row * 128 + col] = acc[rg][cg][j] + b;
      }
  }
}

// ---- edge_fused layer 0: split-input GEMM + epilogue ----
__global__ __launch_bounds__(256) void edge_fused0(
    const unsigned short* __restrict__ ehi, const unsigned short* __restrict__ elo,
    const unsigned short* __restrict__ Wh_g, const unsigned short* __restrict__ Wl_g,
    const float* __restrict__ bias, const int* __restrict__ srcp, const int* __restrict__ dstp,
    const float* __restrict__ Dh, const float* __restrict__ Eh,
    float* __restrict__ ehat, float* __restrict__ epart, int do_stats)
{
  __shared__ unsigned short Ah[64 * 40], Al[64 * 40], Wh[128 * 40], Wl[128 * 40];
  int tid = threadIdx.x;
  long base = (long)blockIdx.x * 64;
  f32x4 acc[4][2];
  mfma_core_split(ehi, elo, base, Wh_g, Wl_g, tid, acc, Ah, Al, Wh, Wl);
  edge_epilogue(acc, bias, srcp, dstp, Dh, Eh, ehat, epart, do_stats, base, tid);
}

// ---- edge_fused layers 1,2: fused e-update staging + GEMM + epilogue ----
template<bool WB>
__global__ __launch_bounds__(256) void edge_fusedU(
    unsigned short* __restrict__ ehi, unsigned short* __restrict__ elo,
    float* __restrict__ ehat,
    const float* __restrict__ scale, const float* __restrict__ shift,
    const unsigned short* __restrict__ Wh_g, const unsigned short* __restrict__ Wl_g,
    const float* __restrict__ bias, const int* __restrict__ srcp, const int* __restrict__ dstp,
    const float* __restrict__ Dh, const float* __restrict__ Eh,
    float* __restrict__ epart, int do_stats)
{
  __shared__ unsigned short Ah[64 * 40], Al[64 * 40], Wh[128 * 40], Wl[128 * 40];
  __shared__ float s_sc[128], s_sh[128];
  int tid = threadIdx.x;
  if (tid < 128) { s_sc[tid] = scale[tid]; s_sh[tid] = shift[tid]; }
  __syncthreads();
  long base = (long)blockIdx.x * 64;
  f32x4 acc[4][2];
  mfma_core_upd<WB>(ehi, elo, ehat, base, Wh_g, Wl_g, s_sc, s_sh, tid, acc, Ah, Al, Wh, Wl);
  edge_epilogue(acc, bias, srcp, dstp, Dh, Eh, ehat, epart, do_stats, base, tid);
}

// ---- generic partial reduce ----
__global__ __launch_bounds__(256) void reduce_part(const float* __restrict__ in,
                                                   float* __restrict__ outp, int groups)
{
  int t = threadIdx.x;
  long base = (long)blockIdx.x * groups * 256;
  float acc = 0.f;
  for (int i = 0; i < groups; ++i) acc += in[base + i * 256 + t];
  outp[(long)blockIdx.x * 256 + t] = acc;
}

__global__ void finalize_bn_p(const float* __restrict__ part, int np, float invn,
                              const float* __restrict__ gamma, const float* __restrict__ beta,
                              float* __restrict__ scale, float* __restrict__ shift)
{
  int c = threadIdx.x;  // 128
  float s = 0.f, q = 0.f;
  for (int p = 0; p < np; ++p) {
    s += part[(long)p * 256 + c];
    q += part[(long)p * 256 + 128 + c];
  }
  float mu = s * invn;
  float var = q * invn - mu * mu;
  float sc = gamma[c] * rsqrtf(var + EPSV);
  scale[c] = sc;
  shift[c] = beta[c] - sc * mu;
}

// ==================== CSR build (by dst) ====================
__global__ __launch_bounds__(256) void hist_dst(const int* __restrict__ dst, int* __restrict__ deg)
{
  int e = blockIdx.x * 256 + threadIdx.x;
  if (e < NE) atomicAdd(&deg[dst[e]], 1);
}

__global__ __launch_bounds__(1024) void scan_deg(const int* __restrict__ deg,
                                                 int* __restrict__ rowstart, int* __restrict__ cursor)
{
  __shared__ int wsum[16];
  __shared__ int carry;
  int tid = threadIdx.x, lane = tid & 63, wid = tid >> 6;
  if (tid == 0) carry = 0;
  __syncthreads();
  for (int base = 0; base < NN; base += 1024) {
    int i = base + tid;
    int v = (i < NN) ? deg[i] : 0;
    int x = v;
    #pragma unroll
    for (int off = 1; off < 64; off <<= 1) {
      int y = __shfl_up(x, off, 64);
      if (lane >= off) x += y;
    }
    if (lane == 63) wsum[wid] = x;
    __syncthreads();
    int wpref = 0;
    for (int j = 0; j < wid; ++j) wpref += wsum[j];
    int excl = carry + wpref + x - v;
    if (i < NN) { rowstart[i] = excl; cursor[i] = excl; }
    __syncthreads();
    if (tid == 1023) carry = excl + v;
    __syncthreads();
  }
  if (tid == 0) rowstart[NN] = NE;
}

__global__ __launch_bounds__(256) void fill_csr(const int* __restrict__ dst,
                                                int* __restrict__ cursor, int* __restrict__ elist)
{
  int e = blockIdx.x * 256 + threadIdx.x;
  if (e < NE) {
    int p = atomicAdd(&cursor[dst[e]], 1);
    elist[p] = e;
  }
}

// ---- deterministic order: sort each node's segment by edge id (deg <= 128 in practice) ----
__global__ __launch_bounds__(128) void seg_sort(const int* __restrict__ rowstart,
                                                int* __restrict__ elist)
{
  __shared__ int buf[MAXD];
  __shared__ int srt[MAXD];
  int n = blockIdx.x;
  int s = rowstart[n], t = rowstart[n + 1];
  int deg = t - s;
  if (deg > MAXD) deg = MAXD;
  int tid = threadIdx.x;
  if (tid < deg) buf[tid] = elist[s + tid];
  __syncthreads();
  if (tid < deg) {
    int v = buf[tid], r = 0;
    for (int j = 0; j < deg; ++j) r += (buf[j] < v);
    srt[r] = v;
  }
  __syncthreads();
  if (tid < deg) elist[s + tid] = srt[tid];
}

// ---- permuted src/dst arrays (slot space) ----
__global__ __launch_bounds__(256) void perm_edges(const int* __restrict__ elist,
                                                  const int* __restrict__ src,
                                                  const int* __restrict__ dst,
                                                  int* __restrict__ srcp, int* __restrict__ dstp)
{
  int s = blockIdx.x * 256 + threadIdx.x;
  if (s < NE) {
    int e = elist[s];
    srcp[s] = src[e];
    dstp[s] = dst[e];
  }
}

// ---- per-node gather, CSR-contiguous: x[n] += sum_k sig(ehat[s+k]) * Bh[srcp[s+k]] ----
__global__ __launch_bounds__(128) void gather_node(
    const float* __restrict__ ehat, const float* __restrict__ Bh, const int* __restrict__ srcp,
    const int* __restrict__ rowstart, float* __restrict__ x)
{
  __shared__ int ssrc[MAXD];
  int n = blockIdx.x;
  int s = rowstart[n], t = rowstart[n + 1];
  int deg = t - s;
  int nload = deg < MAXD ? deg : MAXD;
  int tid = threadIdx.x;
  if (tid < nload) ssrc[tid] = srcp[s + tid];
  __syncthreads();
  float acc = 0.f;
  for (int k = 0; k < nload; ++k)
    acc += sigf(ehat[(long)(s + k) * 128 + tid]) * Bh[(long)ssrc[k] * 128 + tid];
  for (int k = MAXD; k < deg; ++k)  // statistically never taken
    acc += sigf(ehat[(long)(s + k) * 128 + tid]) * Bh[(long)srcp[s + k] * 128 + tid];
  x[(long)n * 128 + tid] += acc;
}

// ---- node BN partials: 250 blocks x 80 rows ----
__global__ __launch_bounds__(256) void stats128p(const float* __restrict__ x, float* __restrict__ part)
{
  __shared__ float red[8][32][8];
  int tid = threadIdx.x, tx = tid & 31, ty = tid >> 5;
  long rbase = (long)blockIdx.x * 80;
  float a0 = 0, a1 = 0, a2 = 0, a3 = 0, c0 = 0, c1 = 0, c2 = 0, c3 = 0;
  #pragma unroll
  for (int i = 0; i < 10; ++i) {
    long row = rbase + i * 8 + ty;
    float4 v = *(const float4*)(x + row * 128 + tx * 4);
    a0 += v.x; a1 += v.y; a2 += v.z; a3 += v.w;
    c0 += v.x * v.x; c1 += v.y * v.y; c2 += v.z * v.z; c3 += v.w * v.w;
  }
  red[ty][tx][0] = a0; red[ty][tx][1] = a1; red[ty][tx][2] = a2; red[ty][tx][3] = a3;
  red[ty][tx][4] = c0; red[ty][tx][5] = c1; red[ty][tx][6] = c2; red[ty][tx][7] = c3;
  __syncthreads();
  if (ty == 0) {
    float b0 = 0, b1 = 0, b2 = 0, b3 = 0, d0 = 0, d1 = 0, d2 = 0, d3 = 0;
    #pragma unroll
    for (int t = 0; t < 8; ++t) {
      b0 += red[t][tx][0]; b1 += red[t][tx][1]; b2 += red[t][tx][2]; b3 += red[t][tx][3];
      d0 += red[t][tx][4]; d1 += red[t][tx][5]; d2 += red[t][tx][6]; d3 += red[t][tx][7];
    }
    float* bp = part + (long)blockIdx.x * 256;
    bp[tx * 4 + 0] = b0; bp[tx * 4 + 1] = b1; bp[tx * 4 + 2] = b2; bp[tx * 4 + 3] = b3;
    bp[128 + tx * 4 + 0] = d0; bp[128 + tx * 4 + 1] = d1;
    bp[128 + tx * 4 + 2] = d2; bp[128 + tx * 4 + 3] = d3;
  }
}

// ---- node pass 2: h += relu(bn(x)) ----
__global__ __launch_bounds__(256) void pass2(
    float* __restrict__ dsta, const float* __restrict__ xv,
    const float* __restrict__ scale, const float* __restrict__ shift, long n4)
{
  long i = (long)blockIdx.x * 256 + threadIdx.x;
  if (i >= n4) return;
  int c = (int)(i & 31) * 4;
  float4 x = ((const float4*)xv)[i];
  float4 sc = *(const float4*)(scale + c);
  float4 sh = *(const float4*)(shift + c);
  float4 d = ((const float4*)dsta)[i];
  d.x += fmaxf(fmaf(sc.x, x.x, sh.x), 0.f);
  d.y += fmaxf(fmaf(sc.y, x.y, sh.y), 0.f);
  d.z += fmaxf(fmaf(sc.z, x.z, sh.z), 0.f);
  d.w += fmaxf(fmaf(sc.w, x.w, sh.w), 0.f);
  ((float4*)dsta)[i] = d;
}

// ---- column-sum partials of h ----
__global__ __launch_bounds__(256) void colsum_p(const float* __restrict__ h, float* __restrict__ hpart)
{
  __shared__ float red[8][32][4];
  int tid = threadIdx.x, tx = tid & 31, ty = tid >> 5;
  long rbase = (long)blockIdx.x * 80;
  float a0 = 0, a1 = 0, a2 = 0, a3 = 0;
  #pragma unroll
  for (int i = 0; i < 10; ++i) {
    long row = rbase + i * 8 + ty;
    float4 v = *(const float4*)(h + row * 128 + tx * 4);
    a0 += v.x; a1 += v.y; a2 += v.z; a3 += v.w;
  }
  red[ty][tx][0] = a0; red[ty][tx][1] = a1; red[ty][tx][2] = a2; red[ty][tx][3] = a3;
  __syncthreads();
  if (ty == 0) {
    float b0 = 0, b1 = 0, b2 = 0, b3 = 0;
    #pragma unroll
    for (int t = 0; t < 8; ++t) {
      b0 += red[t][tx][0]; b1 += red[t][tx][1]; b2 += red[t][tx][2]; b3 += red[t][tx][3];
    }
    float* bp = hpart + (long)blockIdx.x * 128;
    bp[tx * 4 + 0] = b0; bp[tx * 4 + 1] = b1; bp[tx * 4 + 2] = b2; bp[tx * 4 + 3] = b3;
  }
}

__global__ void cls_head(const float* __restrict__ hpart,
                         const float* __restrict__ W1, const float* __restrict__ b1,
                         const float* __restrict__ W2, const float* __restrict__ b2,
                         float* __restrict__ out)
{
  __shared__ float hm[128];
  __shared__ float r1[128];
  int t = threadIdx.x;
  float s = 0.f;
  for (int p = 0; p < 250; ++p) s += hpart[(long)p * 128 + t];
  hm[t] = s * (1.0f / NN);
  __syncthreads();
  float v = b1[t];
  for (int k = 0; k < 128; ++k) v = fmaf(hm[k], W1[k * 128 + t], v);
  r1[t] = fmaxf(v, 0.f);
  __syncthreads();
  if (t < 64) {
    float o = b2[t];
    for (int k = 0; k < 128; ++k) o = fmaf(r1[k], W2[k * 64 + t], o);
    out[t] = o;
  }
}

extern "C" void kernel_launch(void* const* d_in, const int* in_sizes, int n_in,
                              void* d_out, int out_size, void* d_ws, size_t ws_size,
                              hipStream_t stream)
{
  const float* h_in  = (const float*)d_in[0];
  const int*   ei    = (const int*)d_in[1];
  const float* eattr = (const float*)d_in[2];
  const float* nW    = (const float*)d_in[3];
  const float* nb    = (const float*)d_in[4];
  const float* eW    = (const float*)d_in[5];
  const float* eb    = (const float*)d_in[6];
  const float* LW    = (const float*)d_in[7];
  const float* LB    = (const float*)d_in[8];
  const float* G     = (const float*)d_in[9];
  const float* Bt    = (const float*)d_in[10];
  const float* W1    = (const float*)d_in[11];
  const float* b1    = (const float*)d_in[12];
  const float* W2    = (const float*)d_in[13];
  const float* b2    = (const float*)d_in[14];
  float* out = (float*)d_out;

  float* ws = (float*)d_ws;
  float* f_h     = ws;
  float* f_ehat  = f_h    + (long)NN * 128;
  float* f_A     = f_ehat + (long)NE * 128;
  float* f_B     = f_A    + (long)NN * 128;
  float* f_D     = f_B    + (long)NN * 128;
  float* f_E     = f_D    + (long)NN * 128;
  float* f_stats = f_E    + (long)NN * 128;
  float* f_npart = f_stats + S_TOTAL;
  float* f_epart = f_npart + 250 * 256;
  float* f_epart2= f_epart + (long)5000 * 256;
  float* f_hpart = f_epart2 + 50 * 256;
  unsigned short* e_hi = (unsigned short*)(f_hpart + 250 * 128);
  unsigned short* e_lo = e_hi + (long)NE * 128;
  int* i_deg      = (int*)(e_lo + (long)NE * 128);
  int* i_rowstart = i_deg + NN;
  int* i_cursor   = i_rowstart + NN + 1;
  int* i_elist    = i_cursor + NN;
  int* i_srcp     = i_elist + NE;
  int* i_dstp     = i_srcp + NE;
  size_t pw_off = ((((char*)(i_dstp + NE)) - (char*)d_ws) + 15) & ~(size_t)15;
  unsigned short* pw_h = (unsigned short*)((char*)d_ws + pw_off);
  unsigned short* pw_l = pw_h + (long)17 * 16384;
  const int* src = ei;
  const int* dst = ei + NE;

  // ---- weight pre-split ----
  prep_w<<<64, 256, 0, stream>>>(nW, pw_h, pw_l, 1);
  prep_w<<<64, 256, 0, stream>>>(eW, pw_h + 16384, pw_l + 16384, 1);
  prep_w<<<960, 256, 0, stream>>>(LW, pw_h + 2 * 16384, pw_l + 2 * 16384, 15);

  // ---- CSR build + deterministic edge relabeling (slot space) ----
  hipMemsetAsync(i_deg, 0, NN * sizeof(int), stream);
  hist_dst<<<(NE + 255) / 256, 256, 0, stream>>>(dst, i_deg);
  scan_deg<<<1, 1024, 0, stream>>>(i_deg, i_rowstart, i_cursor);
  fill_csr<<<(NE + 255) / 256, 256, 0, stream>>>(dst, i_cursor, i_elist);
  seg_sort<<<NN, 128, 0, stream>>>(i_rowstart, i_elist);
  perm_edges<<<(NE + 255) / 256, 256, 0, stream>>>(i_elist, src, dst, i_srcp, i_dstp);

  // ---- embeddings: h fp32; e split-bf16 directly in slot space ----
  gemm128<<<313, 256, 0, stream>>>(h_in, pw_h, pw_l, nb, f_h, NN);
  gemm128s<<<5000, 256, 0, stream>>>(eattr, i_elist, pw_h + 16384, pw_l + 16384, eb, e_hi, e_lo);

  for (int l = 0; l < NL; ++l) {
    const unsigned short* lwh = pw_h + (long)(2 + l * 5) * 16384;
    const unsigned short* lwl = pw_l + (long)(2 + l * 5) * 16384;
    const float* bl = LB + (long)l * 5 * 128;
    int last = (l == NL - 1);

    gemm128_x4<<<dim3(313, 4), 256, 0, stream>>>(f_h, lwh, lwl, bl, f_A, f_B, f_D, f_E, NN);
    if (l == 0)
      edge_fused0<<<5000, 256, 0, stream>>>(e_hi, e_lo, lwh + 2 * 16384, lwl + 2 * 16384,
                                            bl + 2 * 128, i_srcp, i_dstp, f_D, f_E,
                                            f_ehat, f_epart, 1);
    else if (l == 1)
      edge_fusedU<true><<<5000, 256, 0, stream>>>(e_hi, e_lo, f_ehat,
                                                  f_stats + S_ESC, f_stats + S_ESH,
                                                  lwh + 2 * 16384, lwl + 2 * 16384, bl + 2 * 128,
                                                  i_srcp, i_dstp, f_D, f_E, f_epart, 1);
    else
      edge_fusedU<false><<<5000, 256, 0, stream>>>(e_hi, e_lo, f_ehat,
                                                   f_stats + S_ESC, f_stats + S_ESH,
                                                   lwh + 2 * 16384, lwl + 2 * 16384, bl + 2 * 128,
                                                   i_srcp, i_dstp, f_D, f_E, f_epart, 0);
    if (!last) {
      reduce_part<<<50, 256, 0, stream>>>(f_epart, f_epart2, 100);
      finalize_bn_p<<<1, 128, 0, stream>>>(f_epart2, 50, 1.0f / NE,
                                           G + (l * 2 + 1) * 128, Bt + (l * 2 + 1) * 128,
                                           f_stats + S_ESC, f_stats + S_ESH);
    }
    gather_node<<<NN, 128, 0, stream>>>(f_ehat, f_B, i_srcp, i_rowstart, f_A);
    stats128p<<<250, 256, 0, stream>>>(f_A, f_npart);
    finalize_bn_p<<<1, 128, 0, stream>>>(f_npart, 250, 1.0f / NN,
                                         G + (l * 2 + 0) * 128, Bt + (l * 2 + 0) * 128,
                                         f_stats + S_NSC, f_stats + S_NSH);
    pass2<<<2500, 256, 0, stream>>>(f_h, f_A, f_stats + S_NSC, f_stats + S_NSH, (long)NN * 32);
  }

  colsum_p<<<250, 256, 0, stream>>>(f_h, f_hpart);
  cls_head<<<1, 128, 0, stream>>>(f_hpart, W1, b1, W2, b2, out);
}